// Round 19
// baseline (189.667 us; speedup 1.0000x reference)
//
#include <hip/hip_runtime.h>
#include <hip/hip_bf16.h>
#include <math.h>

constexpr int B_ = 2;
constexpr int T_ = 4096;
constexpr int C_ = 512;
constexpr int H_ = 8;
constexpr int BT_ = B_ * T_;          // 8192 rows
constexpr float EPS_ = 1e-5f;

typedef __attribute__((ext_vector_type(8))) short bf16x8;   // 8 bf16 (4 VGPRs)
typedef __attribute__((ext_vector_type(4))) short short4v;
typedef __attribute__((ext_vector_type(8))) short short8v;
typedef __attribute__((ext_vector_type(4))) float f32x4;

// fp32 -> bf16 round-to-nearest-even (bit hack, cold paths)
__device__ __forceinline__ short f2bf(float f) {
    unsigned int u = __float_as_uint(f);
    unsigned int r = (u + 0x7fffu + ((u >> 16) & 1u)) >> 16;
    return (short)r;
}
__device__ __forceinline__ float bf2f(short s) {
    return __uint_as_float(((unsigned)(unsigned short)s) << 16);
}
// hot path: compiler fuses adjacent pairs into v_cvt_pk_bf16_f32 (m240)
__device__ __forceinline__ short f2bf_h(float f) {
    union { __hip_bfloat16 h; short s; } u;
    u.h = __float2bfloat16(f);
    return u.s;
}
// raw 2^x (1 inst; hw handles large-negative -> 0)
__device__ __forceinline__ float exp2_f(float x) {
    float r;
    asm("v_exp_f32 %0, %1" : "=v"(r) : "v"(x));
    return r;
}

__device__ __forceinline__ float gelu_f(float v) {
    const float k0 = 0.7978845608028654f;   // sqrt(2/pi)
    const float k1 = 0.044715f;
    return 0.5f * v * (1.0f + tanhf(k0 * (v + k1 * v * v * v)));
}

__device__ __forceinline__ void gl_lds16(const short* gsrc, short* lds) {
    __builtin_amdgcn_global_load_lds(
        (const __attribute__((address_space(1))) void*)gsrc,
        (__attribute__((address_space(3))) void*)lds, 16, 0, 0);
}

// ---------------------------------------------------------------------------
// Fused weight transpose + convert for all 4 weights (one launch).
// ---------------------------------------------------------------------------
__global__ __launch_bounds__(256) void transpose_w4(
    const float* __restrict__ W0, short* __restrict__ D0,   // 512x1536
    const float* __restrict__ W1, short* __restrict__ D1,   // 512x512
    const float* __restrict__ W2, short* __restrict__ D2,   // 512x2048
    const float* __restrict__ W3, short* __restrict__ D3) { // 2048x512
    __shared__ float tile[32][33];
    int bid = blockIdx.x;
    const float* W; short* D; int K, N, nx;
    if (bid < 768)       {             W = W0; D = D0; K = 512;  N = 1536; nx = 48; }
    else if (bid < 1024) { bid -= 768;  W = W1; D = D1; K = 512;  N = 512;  nx = 16; }
    else if (bid < 2048) { bid -= 1024; W = W2; D = D2; K = 512;  N = 2048; nx = 64; }
    else                 { bid -= 2048; W = W3; D = D3; K = 2048; N = 512;  nx = 16; }
    const int n0 = (bid % nx) * 32, k0 = (bid / nx) * 32;
    const int tx = threadIdx.x & 31, ty = threadIdx.x >> 5;   // ty 0..7
    #pragma unroll
    for (int j = 0; j < 4; j++)
        tile[ty + j * 8][tx] = W[(size_t)(k0 + ty + j * 8) * N + n0 + tx];
    __syncthreads();
    #pragma unroll
    for (int j = 0; j < 4; j++)
        D[(size_t)(n0 + ty + j * 8) * K + k0 + tx] = f2bf(tile[tx][ty + j * 8]);
}

// ---------------------------------------------------------------------------
// LayerNorm: 256 threads = 4 waves, one row per wave. fp32 in -> bf16 out.
// ---------------------------------------------------------------------------
__global__ __launch_bounds__(256) void ln_bf16(const float* __restrict__ x,
                                               const float* __restrict__ g,
                                               const float* __restrict__ b,
                                               short* __restrict__ out) {
    const int row = blockIdx.x * 4 + (threadIdx.x >> 6);
    const int lane = threadIdx.x & 63;
    const float* xr = x + (size_t)row * C_;

    float4 v0 = *(const float4*)(xr + lane * 8);
    float4 v1 = *(const float4*)(xr + lane * 8 + 4);

    float s  = v0.x + v0.y + v0.z + v0.w + v1.x + v1.y + v1.z + v1.w;
    float s2 = v0.x*v0.x + v0.y*v0.y + v0.z*v0.z + v0.w*v0.w
             + v1.x*v1.x + v1.y*v1.y + v1.z*v1.z + v1.w*v1.w;
    #pragma unroll
    for (int off = 32; off; off >>= 1) {
        s  += __shfl_down(s, off);
        s2 += __shfl_down(s2, off);
    }
    s  = __shfl(s, 0);
    s2 = __shfl(s2, 0);

    const float mu  = s * (1.0f / C_);
    const float var = s2 * (1.0f / C_) - mu * mu;
    const float rs  = rsqrtf(var + EPS_);

    float4 g0 = *(const float4*)(g + lane * 8);
    float4 g1 = *(const float4*)(g + lane * 8 + 4);
    float4 b0 = *(const float4*)(b + lane * 8);
    float4 b1 = *(const float4*)(b + lane * 8 + 4);

    short8v o;
    o[0] = f2bf((v0.x - mu) * rs * g0.x + b0.x);
    o[1] = f2bf((v0.y - mu) * rs * g0.y + b0.y);
    o[2] = f2bf((v0.z - mu) * rs * g0.z + b0.z);
    o[3] = f2bf((v0.w - mu) * rs * g0.w + b0.w);
    o[4] = f2bf((v1.x - mu) * rs * g1.x + b1.x);
    o[5] = f2bf((v1.y - mu) * rs * g1.y + b1.y);
    o[6] = f2bf((v1.z - mu) * rs * g1.z + b1.z);
    o[7] = f2bf((v1.w - mu) * rs * g1.w + b1.w);
    *(short8v*)(out + (size_t)row * C_ + lane * 8) = o;
}

// ---------------------------------------------------------------------------
// bf16 MFMA GEMM, 64x128x128 tile, SINGLE-buffered (r17-proven config).
// 256B LDS rows, chunk-XOR swizzle; frag read chunk = (4j+g)^(c&7).
// VFUSE=1 (qkv): n0>=1024 tiles write acc into Vt with kv-permutation.
// SPLITK=1 (mlp-proj): 2 K-halves per output tile; both atomicAdd into
// d_out (which already holds x2 from step 4); kk==0 half adds bias.
// ---------------------------------------------------------------------------
template<int BM, int ACT, int OUTBF16, int HASRES, int VFUSE, int SPLITK>
__global__ __launch_bounds__(256) void gemm_bf16(const short* __restrict__ A,
                                                 const short* __restrict__ Wt,
                                                 const float* __restrict__ bias,
                                                 const float* __restrict__ res,
                                                 void* __restrict__ outp,
                                                 int M, int N, int K,
                                                 int GX, int CY,
                                                 short* __restrict__ vtb) {
    constexpr int BK   = (BM == 128) ? 64 : 128;
    constexpr int MT   = BM / 32;            // A frags per wave
    constexpr int JMAX = BK / 32;            // k-steps per buffer
    constexpr int CPR  = BK / 8;             // 16B chunks per row
    constexpr int RPI  = 256 / CPR;          // rows per staging issue
    constexpr int AISS = BM / RPI;           // A staging issues
    constexpr int BISS = 128 / RPI;          // B staging issues

    __shared__ short As[BM * BK];
    __shared__ short Bs[128 * BK];

    const int bid = blockIdx.x;
    const int xcd = bid & 7;
    int jb = bid >> 3;
    int koff = 0;
    if (SPLITK) { koff = (jb & 1) * (K >> 1); jb >>= 1; }
    const int by = xcd * CY + jb / GX;
    const int bx = jb % GX;

    const int t = threadIdx.x;
    const int w = t >> 6;
    const int l = t & 63;
    const int c = l & 15;
    const int g = l >> 4;
    const int wr = w >> 1, wc = w & 1;
    const int m0 = by * BM, n0 = bx * 128;

    // staging addressing (LDS linear dest == (RPI*i+rt)*BK + ct*8)
    const int rt  = t / CPR;
    const int sch = ((t % CPR) ^ (rt & 7)) * 8;       // shorts
    const short* Asrc = A  + (size_t)(m0 + rt) * K + sch;
    const short* Bsrc = Wt + (size_t)(n0 + rt) * K + sch;

    auto stage = [&](int kt) {
        #pragma unroll
        for (int i = 0; i < AISS; i++)
            gl_lds16(Asrc + (size_t)(RPI * i) * K + kt, &As[i * 2048 + w * 512]);
        #pragma unroll
        for (int i = 0; i < BISS; i++)
            gl_lds16(Bsrc + (size_t)(RPI * i) * K + kt, &Bs[i * 2048 + w * 512]);
    };

    f32x4 acc[MT][4] = {};

    const int kend = SPLITK ? (koff + (K >> 1)) : K;
    for (int kt = koff; kt < kend; kt += BK) {
        stage(kt);
        __syncthreads();     // drains vmcnt (gl_lds) for all waves

        #pragma unroll
        for (int j = 0; j < JMAX; j++) {
            const int ckj = ((4 * j + g) ^ (c & 7)) * 8;   // shorts
            bf16x8 af[MT], bfr[4];
            #pragma unroll
            for (int mt = 0; mt < MT; mt++)
                af[mt] = *(const bf16x8*)&As[(wr * (BM / 2) + mt * 16 + c) * BK + ckj];
            #pragma unroll
            for (int nt = 0; nt < 4; nt++)
                bfr[nt] = *(const bf16x8*)&Bs[(wc * 64 + nt * 16 + c) * BK + ckj];
            #pragma unroll
            for (int mt = 0; mt < MT; mt++)
                #pragma unroll
                for (int nt = 0; nt < 4; nt++)
                    acc[mt][nt] = __builtin_amdgcn_mfma_f32_16x16x32_bf16(
                        af[mt], bfr[nt], acc[mt][nt], 0, 0, 0);
        }

        __syncthreads();     // all reads done before next stage overwrites
    }

    const int colb = n0 + wc * 64;
    float bias_v[4];
    #pragma unroll
    for (int nt = 0; nt < 4; nt++) bias_v[nt] = bias[colb + nt * 16 + c];

    if (VFUSE && n0 >= 1024) {
        // V-fused epilogue: Vt[(b*8+h)*64+d][t'] = bf16(acc + bias)
        const int bq   = m0 >> 12;                       // batch index
        const int trow = (m0 & 4095) + wr * (BM / 2);    // t base (&~31 part)
        #pragma unroll
        for (int mt = 0; mt < MT; mt++) {
            const int tb = trow + (mt >> 1) * 32 + 8 * g + 4 * (mt & 1);
            #pragma unroll
            for (int nt = 0; nt < 4; nt++) {
                const int vcol = colb + nt * 16 + c - 1024;
                const int hh = vcol >> 6, dd = vcol & 63;
                short4v pk;
                #pragma unroll
                for (int rr = 0; rr < 4; rr++)
                    pk[rr] = f2bf(acc[mt][nt][rr] + bias_v[nt]);
                *(short4v*)&vtb[((size_t)((bq * 8 + hh) * 64 + dd)) * T_ + tb] = pk;
            }
        }
        return;
    }

    float* out_f = (float*)outp;
    short* out_h = (short*)outp;

    if (SPLITK) {
        // d_out already holds x2 (step 4); both K-halves accumulate onto it.
        const bool addb = (koff == 0);
        #pragma unroll
        for (int mt = 0; mt < MT; mt++) {
            #pragma unroll
            for (int rr = 0; rr < 4; rr++) {
                const size_t row = (size_t)(m0 + wr * (BM / 2) + mt * 16 + 4 * g + rr);
                #pragma unroll
                for (int nt = 0; nt < 4; nt++) {
                    const int col = colb + nt * 16 + c;
                    float v = acc[mt][nt][rr] + (addb ? bias_v[nt] : 0.0f);
                    atomicAdd(&out_f[row * N + col], v);
                }
            }
        }
        return;
    }

    #pragma unroll
    for (int mt = 0; mt < MT; mt++) {
        #pragma unroll
        for (int rr = 0; rr < 4; rr++) {
            const size_t row = (size_t)(m0 + wr * (BM / 2) + mt * 16 + 4 * g + rr);
            #pragma unroll
            for (int nt = 0; nt < 4; nt++) {
                const int col = colb + nt * 16 + c;
                float v = acc[mt][nt][rr] + bias_v[nt];
                if (ACT) v = gelu_f(v);
                if (HASRES) v += res[row * N + col];
                if (OUTBF16) out_h[row * N + col] = f2bf(v);
                else         out_f[row * N + col] = v;
            }
        }
    }
}

// ---------------------------------------------------------------------------
// Flash attention, bf16 MFMA. 1024 blocks x 256 threads (4 waves).
// qtr->qt permutation: qt = qtr<32 ? 63-qtr : qtr-32 (uniform 130 iters/CU
// under breadth-first round-robin dispatch — verified round 12).
// XCD-bijective (b,h) map; fixed-shift softmax; l via ones-MFMA; ping-pong.
// ---------------------------------------------------------------------------
__global__ __launch_bounds__(256) void attn_mfma(const short* __restrict__ qkv,
                                                 const short* __restrict__ Vt,
                                                 short* __restrict__ y) {
    __shared__ union {
        struct { short K[2][64 * 64]; short V[2][64 * 64]; } s;   // 32 KB
        float O[4][16][68];                                       // 17 KB
    } sm;

    // bid = xcd + 8*(lo*64 + qtr); balanced pairing permutation
    const int bid = blockIdx.x;
    const int xcd = bid & 7, jj = bid >> 3;
    const int lo = jj >> 6;
    const int qtr = jj & 63;
    const int qt = (qtr < 32) ? (63 - qtr) : (qtr - 32);
    const int g16 = xcd * 2 + lo;
    const int b = g16 >> 3, h = g16 & 7;

    const int tid = threadIdx.x, w = tid >> 6, lid = tid & 63;
    const int c = lid & 15, g = lid >> 4;
    const size_t base = (size_t)b * T_;
    const int bh = g16;

    const float qmul = 0.04419417382415922f * 1.4426950408889634f; // 1/sqrt(512)*log2e

    // Q fragment (B operand), pre-scaled
    bf16x8 qf0, qf1;
    {
        const short* qa = qkv + (base + qt * 64 + w * 16 + c) * 1536 + h * 64 + g * 8;
        bf16x8 a0 = *(const bf16x8*)qa;
        bf16x8 a1 = *(const bf16x8*)(qa + 32);
        #pragma unroll
        for (int i = 0; i < 8; i++) {
            qf0[i] = f2bf_h(bf2f(a0[i]) * qmul);
            qf1[i] = f2bf_h(bf2f(a1[i]) * qmul);
        }
    }

    const f32x4 kZero = {0.f, 0.f, 0.f, 0.f};
    bf16x8 kOnes;
    #pragma unroll
    for (int i = 0; i < 8; i++) kOnes[i] = (short)0x3F80;   // bf16 1.0

    f32x4 ot[4] = {};
    f32x4 lacc = {0.f, 0.f, 0.f, 0.f};   // l via ones-MFMA
    const int qg = qt * 64 + w * 16 + c;

    const int sr = tid >> 3;                         // 0..31
    const int sc = ((tid & 7) ^ (sr & 7)) * 8;       // swizzled source chunk

    auto stage = [&](short* Kb, short* Vb, int st) {
        const short* ks = qkv + (base + st * 64 + sr) * 1536 + 512 + h * 64 + sc;
        const short* vs = Vt + ((size_t)(bh * 64 + sr)) * T_ + st * 64 + sc;
        gl_lds16(ks, Kb + w * 512);
        gl_lds16(ks + (size_t)32 * 1536, Kb + 2048 + w * 512);
        gl_lds16(vs, Vb + w * 512);
        gl_lds16(vs + (size_t)32 * T_, Vb + 2048 + w * 512);
    };

    const int rx = c & 7;
    const int ck0 = g ^ rx;              // LDS chunk for source chunk g
    const int ck1 = ck0 ^ 4;             // LDS chunk for source chunk 4+g

    // full tile: QK^T -> exp2 -> l(ones-MFMA) -> PV
    auto tile = [&](const short* Kb, const short* Vb, bool mask_diag) {
        f32x4 s[4];
        __builtin_amdgcn_s_setprio(1);
        #pragma unroll
        for (int mt = 0; mt < 4; mt++) {
            const short* krow = Kb + (mt * 16 + c) * 64;
            bf16x8 k0 = *(const bf16x8*)&krow[ck0 * 8];
            bf16x8 k1 = *(const bf16x8*)&krow[ck1 * 8];
            f32x4 z = __builtin_amdgcn_mfma_f32_16x16x32_bf16(k0, qf0, kZero, 0, 0, 0);
            s[mt] = __builtin_amdgcn_mfma_f32_16x16x32_bf16(k1, qf1, z, 0, 0, 0);
        }
        __builtin_amdgcn_s_setprio(0);

        float p[4][4];
        #pragma unroll
        for (int mt = 0; mt < 4; mt++)
            #pragma unroll
            for (int rr = 0; rr < 4; rr++) {
                float v = s[mt][rr];
                if (mask_diag && (qt * 64 + mt * 16 + 4 * g + rr > qg)) v = -1e30f;
                p[mt][rr] = exp2_f(v);          // exp2(-1e30) -> 0
            }

        bf16x8 pb0, pb1;
        #pragma unroll
        for (int i = 0; i < 8; i++) {
            pb0[i] = f2bf_h(p[(i >> 2)][i & 3]);
            pb1[i] = f2bf_h(p[2 + (i >> 2)][i & 3]);
        }
        __builtin_amdgcn_s_setprio(1);
        // l contribution on the matrix pipe: out[r][c] = sum_k p[k][c]
        lacc = __builtin_amdgcn_mfma_f32_16x16x32_bf16(kOnes, pb0, lacc, 0, 0, 0);
        lacc = __builtin_amdgcn_mfma_f32_16x16x32_bf16(kOnes, pb1, lacc, 0, 0, 0);
        #pragma unroll
        for (int dt = 0; dt < 4; dt++) {
            const short* vrow = Vb + (16 * dt + c) * 64;
            bf16x8 va0 = *(const bf16x8*)&vrow[ck0 * 8];
            bf16x8 va1 = *(const bf16x8*)&vrow[ck1 * 8];
            ot[dt] = __builtin_amdgcn_mfma_f32_16x16x32_bf16(va0, pb0, ot[dt], 0, 0, 0);
            ot[dt] = __builtin_amdgcn_mfma_f32_16x16x32_bf16(va1, pb1, ot[dt], 0, 0, 0);
        }
        __builtin_amdgcn_s_setprio(0);
    };

    short* K0 = sm.s.K[0]; short* K1 = sm.s.K[1];
    short* V0 = sm.s.V[0]; short* V1 = sm.s.V[1];

    stage(K0, V0, 0);
    asm volatile("s_waitcnt vmcnt(0)" ::: "memory");
    __syncthreads();

    int st = 0;
    while (st + 2 <= qt) {              // pairs of common (maskless) tiles
        stage(K1, V1, st + 1);
        tile(K0, V0, false);
        asm volatile("s_waitcnt vmcnt(0)" ::: "memory");
        __syncthreads();
        stage(K0, V0, st + 2);
        tile(K1, V1, false);
        asm volatile("s_waitcnt vmcnt(0)" ::: "memory");
        __syncthreads();
        st += 2;
    }
    if (st < qt) {                      // one common + diagonal in buf1
        stage(K1, V1, st + 1);
        tile(K0, V0, false);
        asm volatile("s_waitcnt vmcnt(0)" ::: "memory");
        __syncthreads();
        tile(K1, V1, true);
    } else {                            // diagonal in buf0
        tile(K0, V0, true);
    }
    __syncthreads();   // all waves done with K/V before union reuse as O

    // epilogue: O^T/l -> LDS transpose.  l = lacc[0] (all regs identical)
    const float inv = 1.0f / lacc[0];
    #pragma unroll
    for (int dt = 0; dt < 4; dt++)
        #pragma unroll
        for (int rr = 0; rr < 4; rr++)
            sm.O[w][c][16 * dt + 4 * g + rr] = ot[dt][rr] * inv;
    // wave-local write->read (per-wave LDS ordering + compiler lgkmcnt)
    const int q = lid >> 2, ch = lid & 3;
    short* dst = y + (base + qt * 64 + w * 16 + q) * 512 + h * 64 + ch * 16;
    short8v o0, o1;
    #pragma unroll
    for (int j = 0; j < 8; j++) o0[j] = f2bf(sm.O[w][q][ch * 16 + j]);
    #pragma unroll
    for (int j = 0; j < 8; j++) o1[j] = f2bf(sm.O[w][q][ch * 16 + 8 + j]);
    *(short8v*)dst = o0;
    *(short8v*)(dst + 8) = o1;
}

// ---------------------------------------------------------------------------
// Orchestration
// ---------------------------------------------------------------------------
extern "C" void kernel_launch(void* const* d_in, const int* in_sizes, int n_in,
                              void* d_out, int out_size, void* d_ws, size_t ws_size,
                              hipStream_t stream) {
    const float* x           = (const float*)d_in[0];
    const float* w_qkv       = (const float*)d_in[1];
    const float* b_qkv       = (const float*)d_in[2];
    const float* w_attn_proj = (const float*)d_in[3];
    const float* b_attn_proj = (const float*)d_in[4];
    const float* w_fc        = (const float*)d_in[5];
    const float* b_fc        = (const float*)d_in[6];
    const float* w_mlp_proj  = (const float*)d_in[7];
    const float* b_mlp_proj  = (const float*)d_in[8];
    const float* ln1_g       = (const float*)d_in[9];
    const float* ln1_b       = (const float*)d_in[10];
    const float* ln2_g       = (const float*)d_in[11];
    const float* ln2_b       = (const float*)d_in[12];

    float* out = (float*)d_out;
    short* ws16 = (short*)d_ws;

    // ws layout (bf16 elems), ~65 MB total
    short* wqkvT = ws16;                                   // [1536][512]
    short* waT   = wqkvT + 1536 * 512;                     // [512][512]
    short* wfcT  = waT   + 512 * 512;                      // [2048][512]
    short* wmT   = wfcT  + 2048 * 512;                     // [512][2048]
    short* xn    = wmT   + 512 * 2048;                     // [8192][512]
    short* ybuf  = xn    + (size_t)BT_ * 512;              // [8192][512]
    short* qkvh  = ybuf  + (size_t)BT_ * 512;              // [8192][2048] (q|k|unused, h)
    short* vtb   = qkvh  + (size_t)BT_ * 2048;             // [2][8][64][4096]

    // 0) weights -> bf16 transposed (single fused launch)
    transpose_w4<<<3072, 256, 0, stream>>>(w_qkv, wqkvT, w_attn_proj, waT,
                                           w_fc, wfcT, w_mlp_proj, wmT);

    // 1) xn1 = LN(x)
    ln_bf16<<<BT_ / 4, 256, 0, stream>>>(x, ln1_g, ln1_b, xn);

    // 2) qkv = xn1 @ w_qkv + b_qkv  (bf16 out; V-region fused into Vt)
    //    r17-proven: BM=64, grid 12 x 128, GX=12 CY=16
    gemm_bf16<64, 0, 1, 0, 1, 0><<<12 * 128, 256, 0, stream>>>(
        xn, wqkvT, b_qkv, nullptr, qkvh, BT_, 1536, 512, 12, 16, vtb);

    // 3) y = attention(qkv, Vt)  (bf16 out) — 1024 blocks, balanced pairing
    attn_mfma<<<1024, 256, 0, stream>>>(qkvh, vtb, ybuf);

    // 4) x2 = x + y @ w_attn_proj + b  (f32 out -> d_out)  BM=64, GX=4 CY=16
    gemm_bf16<64, 0, 0, 1, 0, 0><<<4 * 128, 256, 0, stream>>>(
        ybuf, waT, b_attn_proj, x, out, BT_, 512, 512, 4, 16, nullptr);

    // 5) xn2 = LN(x2)
    ln_bf16<<<BT_ / 4, 256, 0, stream>>>(out, ln2_g, ln2_b, xn);

    // 6) h = gelu(xn2 @ w_fc + b)  (bf16 out)  r17: BM=64, grid 16 x 128
    gemm_bf16<64, 1, 1, 0, 0, 0><<<16 * 128, 256, 0, stream>>>(
        xn, wfcT, b_fc, nullptr, qkvh, BT_, 2048, 512, 16, 16, nullptr);

    // 7) out(x2) += h @ w_mlp_proj + b  — SPLIT-K=2, atomicAdd onto x2
    //    grid 1024 = 128 M x 4 N x 2 K-halves
    gemm_bf16<64, 0, 0, 0, 0, 1><<<1024, 256, 0, stream>>>(
        qkvh, wmT, b_mlp_proj, nullptr, out, BT_, 512, 2048, 4, 16, nullptr);
}

// Round 20
// 173.374 us; speedup vs baseline: 1.0940x; 1.0940x over previous
//
#include <hip/hip_runtime.h>
#include <hip/hip_bf16.h>
#include <math.h>

constexpr int B_ = 2;
constexpr int T_ = 4096;
constexpr int C_ = 512;
constexpr int H_ = 8;
constexpr int BT_ = B_ * T_;          // 8192 rows
constexpr float EPS_ = 1e-5f;

typedef __attribute__((ext_vector_type(8))) short bf16x8;   // 8 bf16 (4 VGPRs)
typedef __attribute__((ext_vector_type(4))) short short4v;
typedef __attribute__((ext_vector_type(8))) short short8v;
typedef __attribute__((ext_vector_type(4))) float f32x4;

// fp32 -> bf16 round-to-nearest-even (bit hack, cold paths)
__device__ __forceinline__ short f2bf(float f) {
    unsigned int u = __float_as_uint(f);
    unsigned int r = (u + 0x7fffu + ((u >> 16) & 1u)) >> 16;
    return (short)r;
}
__device__ __forceinline__ float bf2f(short s) {
    return __uint_as_float(((unsigned)(unsigned short)s) << 16);
}
// hot path: compiler fuses adjacent pairs into v_cvt_pk_bf16_f32 (m240)
__device__ __forceinline__ short f2bf_h(float f) {
    union { __hip_bfloat16 h; short s; } u;
    u.h = __float2bfloat16(f);
    return u.s;
}
// raw 2^x (1 inst; hw handles large-negative -> 0)
__device__ __forceinline__ float exp2_f(float x) {
    float r;
    asm("v_exp_f32 %0, %1" : "=v"(r) : "v"(x));
    return r;
}

__device__ __forceinline__ float gelu_f(float v) {
    const float k0 = 0.7978845608028654f;   // sqrt(2/pi)
    const float k1 = 0.044715f;
    return 0.5f * v * (1.0f + tanhf(k0 * (v + k1 * v * v * v)));
}

__device__ __forceinline__ void gl_lds16(const short* gsrc, short* lds) {
    __builtin_amdgcn_global_load_lds(
        (const __attribute__((address_space(1))) void*)gsrc,
        (__attribute__((address_space(3))) void*)lds, 16, 0, 0);
}

// ---------------------------------------------------------------------------
// Fused weight transpose + convert for all 4 weights (one launch).
// ---------------------------------------------------------------------------
__global__ __launch_bounds__(256) void transpose_w4(
    const float* __restrict__ W0, short* __restrict__ D0,   // 512x1536
    const float* __restrict__ W1, short* __restrict__ D1,   // 512x512
    const float* __restrict__ W2, short* __restrict__ D2,   // 512x2048
    const float* __restrict__ W3, short* __restrict__ D3) { // 2048x512
    __shared__ float tile[32][33];
    int bid = blockIdx.x;
    const float* W; short* D; int K, N, nx;
    if (bid < 768)       {             W = W0; D = D0; K = 512;  N = 1536; nx = 48; }
    else if (bid < 1024) { bid -= 768;  W = W1; D = D1; K = 512;  N = 512;  nx = 16; }
    else if (bid < 2048) { bid -= 1024; W = W2; D = D2; K = 512;  N = 2048; nx = 64; }
    else                 { bid -= 2048; W = W3; D = D3; K = 2048; N = 512;  nx = 16; }
    const int n0 = (bid % nx) * 32, k0 = (bid / nx) * 32;
    const int tx = threadIdx.x & 31, ty = threadIdx.x >> 5;   // ty 0..7
    #pragma unroll
    for (int j = 0; j < 4; j++)
        tile[ty + j * 8][tx] = W[(size_t)(k0 + ty + j * 8) * N + n0 + tx];
    __syncthreads();
    #pragma unroll
    for (int j = 0; j < 4; j++)
        D[(size_t)(n0 + ty + j * 8) * K + k0 + tx] = f2bf(tile[tx][ty + j * 8]);
}

// ---------------------------------------------------------------------------
// LayerNorm: 256 threads = 4 waves, one row per wave. fp32 in -> bf16 out.
// ---------------------------------------------------------------------------
__global__ __launch_bounds__(256) void ln_bf16(const float* __restrict__ x,
                                               const float* __restrict__ g,
                                               const float* __restrict__ b,
                                               short* __restrict__ out) {
    const int row = blockIdx.x * 4 + (threadIdx.x >> 6);
    const int lane = threadIdx.x & 63;
    const float* xr = x + (size_t)row * C_;

    float4 v0 = *(const float4*)(xr + lane * 8);
    float4 v1 = *(const float4*)(xr + lane * 8 + 4);

    float s  = v0.x + v0.y + v0.z + v0.w + v1.x + v1.y + v1.z + v1.w;
    float s2 = v0.x*v0.x + v0.y*v0.y + v0.z*v0.z + v0.w*v0.w
             + v1.x*v1.x + v1.y*v1.y + v1.z*v1.z + v1.w*v1.w;
    #pragma unroll
    for (int off = 32; off; off >>= 1) {
        s  += __shfl_down(s, off);
        s2 += __shfl_down(s2, off);
    }
    s  = __shfl(s, 0);
    s2 = __shfl(s2, 0);

    const float mu  = s * (1.0f / C_);
    const float var = s2 * (1.0f / C_) - mu * mu;
    const float rs  = rsqrtf(var + EPS_);

    float4 g0 = *(const float4*)(g + lane * 8);
    float4 g1 = *(const float4*)(g + lane * 8 + 4);
    float4 b0 = *(const float4*)(b + lane * 8);
    float4 b1 = *(const float4*)(b + lane * 8 + 4);

    short8v o;
    o[0] = f2bf((v0.x - mu) * rs * g0.x + b0.x);
    o[1] = f2bf((v0.y - mu) * rs * g0.y + b0.y);
    o[2] = f2bf((v0.z - mu) * rs * g0.z + b0.z);
    o[3] = f2bf((v0.w - mu) * rs * g0.w + b0.w);
    o[4] = f2bf((v1.x - mu) * rs * g1.x + b1.x);
    o[5] = f2bf((v1.y - mu) * rs * g1.y + b1.y);
    o[6] = f2bf((v1.z - mu) * rs * g1.z + b1.z);
    o[7] = f2bf((v1.w - mu) * rs * g1.w + b1.w);
    *(short8v*)(out + (size_t)row * C_ + lane * 8) = o;
}

// ---------------------------------------------------------------------------
// bf16 MFMA GEMM, 64x128x128 tile, SINGLE-buffered (48 KB LDS, 3 blocks/CU).
// BK=128: fewest staging windows (the proven lever; r18/r19 variants both
// regressed — this is the measured local optimum, 173.6 us total).
// 256B LDS rows, chunk-XOR swizzle: LDS[row][ck] = src[row][ck ^ (row&7)]
// (16B chunks, 16 per row); frag read chunk = (4j+g) ^ (c&7) for k-step j.
// VFUSE=1 (qkv GEMM): n0>=1024 tiles write acc directly into Vt with the
// kv-permutation t' = (t&~31)|(8g+4*mt+rr)  (BM=64: t%32 = 16*mt+4g+rr).
// ---------------------------------------------------------------------------
template<int ACT, int OUTBF16, int HASRES, int VFUSE>
__global__ __launch_bounds__(256) void gemm_bf16(const short* __restrict__ A,
                                                 const short* __restrict__ Wt,
                                                 const float* __restrict__ bias,
                                                 const float* __restrict__ res,
                                                 void* __restrict__ outp,
                                                 int M, int N, int K,
                                                 int GX, int CY,
                                                 short* __restrict__ vtb) {
    __shared__ short As[64 * 128];       // 16 KB
    __shared__ short Bs[128 * 128];      // 32 KB

    const int bid = blockIdx.x;
    const int xcd = bid & 7, jb = bid >> 3;
    const int by = xcd * CY + jb / GX;
    const int bx = jb % GX;

    const int t = threadIdx.x;
    const int w = t >> 6;
    const int l = t & 63;
    const int c = l & 15;
    const int g = l >> 4;
    const int wr = w >> 1, wc = w & 1;
    const int m0 = by * 64, n0 = bx * 128;

    // staging: 256 threads cover 16 rows x 16 chunks per issue.
    // r16 = t>>4 (= 4w+g), chunk ct = t&15; source chunk = ct ^ (r16&7).
    // dest is linear in t (wave-uniform base + lane*16) = row-major LDS.
    const int r16 = t >> 4;
    const int sch = ((t & 15) ^ (r16 & 7)) * 8;       // shorts
    const short* Asrc = A  + (size_t)(m0 + r16) * K + sch;
    const short* Bsrc = Wt + (size_t)(n0 + r16) * K + sch;

    auto stage = [&](int kt) {
        #pragma unroll
        for (int i = 0; i < 4; i++)
            gl_lds16(Asrc + (size_t)(16 * i) * K + kt, &As[i * 2048 + w * 512]);
        #pragma unroll
        for (int i = 0; i < 8; i++)
            gl_lds16(Bsrc + (size_t)(16 * i) * K + kt, &Bs[i * 2048 + w * 512]);
    };

    f32x4 acc[2][4] = {};

    for (int kt = 0; kt < K; kt += 128) {
        stage(kt);
        __syncthreads();     // drains vmcnt (gl_lds) for all waves

        #pragma unroll
        for (int j = 0; j < 4; j++) {     // k-steps of 32 within the 128
            const int ckj = ((4 * j + g) ^ (c & 7)) * 8;   // shorts
            bf16x8 af[2], bfr[4];
            #pragma unroll
            for (int mt = 0; mt < 2; mt++)
                af[mt] = *(const bf16x8*)&As[(wr * 32 + mt * 16 + c) * 128 + ckj];
            #pragma unroll
            for (int nt = 0; nt < 4; nt++)
                bfr[nt] = *(const bf16x8*)&Bs[(wc * 64 + nt * 16 + c) * 128 + ckj];
            #pragma unroll
            for (int mt = 0; mt < 2; mt++)
                #pragma unroll
                for (int nt = 0; nt < 4; nt++)
                    acc[mt][nt] = __builtin_amdgcn_mfma_f32_16x16x32_bf16(
                        af[mt], bfr[nt], acc[mt][nt], 0, 0, 0);
        }

        __syncthreads();     // all reads done before next stage overwrites
    }

    const int colb = n0 + wc * 64;
    float bias_v[4];
    #pragma unroll
    for (int nt = 0; nt < 4; nt++) bias_v[nt] = bias[colb + nt * 16 + c];

    if (VFUSE && n0 >= 1024) {
        // V-fused epilogue: Vt[(b*8+h)*64+d][t'] = bf16(acc + bias)
        const int bq   = m0 >> 12;                 // batch index
        const int trow = (m0 & 4095) + wr * 32;    // t base (&~31 part)
        #pragma unroll
        for (int mt = 0; mt < 2; mt++) {
            const int tb = trow + 8 * g + 4 * mt;
            #pragma unroll
            for (int nt = 0; nt < 4; nt++) {
                const int vcol = colb + nt * 16 + c - 1024;
                const int hh = vcol >> 6, dd = vcol & 63;
                short4v pk;
                #pragma unroll
                for (int rr = 0; rr < 4; rr++)
                    pk[rr] = f2bf(acc[mt][nt][rr] + bias_v[nt]);
                *(short4v*)&vtb[((size_t)((bq * 8 + hh) * 64 + dd)) * T_ + tb] = pk;
            }
        }
        return;
    }

    float* out_f = (float*)outp;
    short* out_h = (short*)outp;

    #pragma unroll
    for (int mt = 0; mt < 2; mt++) {
        #pragma unroll
        for (int rr = 0; rr < 4; rr++) {
            const size_t row = (size_t)(m0 + wr * 32 + mt * 16 + 4 * g + rr);
            #pragma unroll
            for (int nt = 0; nt < 4; nt++) {
                const int col = colb + nt * 16 + c;
                float v = acc[mt][nt][rr] + bias_v[nt];
                if (ACT) v = gelu_f(v);
                if (HASRES) v += res[row * N + col];
                if (OUTBF16) out_h[row * N + col] = f2bf(v);
                else         out_f[row * N + col] = v;
            }
        }
    }
}

// ---------------------------------------------------------------------------
// Flash attention, bf16 MFMA. 1024 blocks x 256 threads (4 waves).
// qtr->qt permutation: qt = qtr<32 ? 63-qtr : qtr-32 (uniform 130 iters/CU
// under breadth-first round-robin dispatch — verified round 12).
// XCD-bijective (b,h) map; fixed-shift softmax; l via ones-MFMA; ping-pong.
// ---------------------------------------------------------------------------
__global__ __launch_bounds__(256) void attn_mfma(const short* __restrict__ qkv,
                                                 const short* __restrict__ Vt,
                                                 short* __restrict__ y) {
    __shared__ union {
        struct { short K[2][64 * 64]; short V[2][64 * 64]; } s;   // 32 KB
        float O[4][16][68];                                       // 17 KB
    } sm;

    // bid = xcd + 8*(lo*64 + qtr); balanced pairing permutation
    const int bid = blockIdx.x;
    const int xcd = bid & 7, jj = bid >> 3;
    const int lo = jj >> 6;
    const int qtr = jj & 63;
    const int qt = (qtr < 32) ? (63 - qtr) : (qtr - 32);
    const int g16 = xcd * 2 + lo;
    const int b = g16 >> 3, h = g16 & 7;

    const int tid = threadIdx.x, w = tid >> 6, lid = tid & 63;
    const int c = lid & 15, g = lid >> 4;
    const size_t base = (size_t)b * T_;
    const int bh = g16;

    const float qmul = 0.04419417382415922f * 1.4426950408889634f; // 1/sqrt(512)*log2e

    // Q fragment (B operand), pre-scaled
    bf16x8 qf0, qf1;
    {
        const short* qa = qkv + (base + qt * 64 + w * 16 + c) * 1536 + h * 64 + g * 8;
        bf16x8 a0 = *(const bf16x8*)qa;
        bf16x8 a1 = *(const bf16x8*)(qa + 32);
        #pragma unroll
        for (int i = 0; i < 8; i++) {
            qf0[i] = f2bf_h(bf2f(a0[i]) * qmul);
            qf1[i] = f2bf_h(bf2f(a1[i]) * qmul);
        }
    }

    const f32x4 kZero = {0.f, 0.f, 0.f, 0.f};
    bf16x8 kOnes;
    #pragma unroll
    for (int i = 0; i < 8; i++) kOnes[i] = (short)0x3F80;   // bf16 1.0

    f32x4 ot[4] = {};
    f32x4 lacc = {0.f, 0.f, 0.f, 0.f};   // l via ones-MFMA
    const int qg = qt * 64 + w * 16 + c;

    const int sr = tid >> 3;                         // 0..31
    const int sc = ((tid & 7) ^ (sr & 7)) * 8;       // swizzled source chunk

    auto stage = [&](short* Kb, short* Vb, int st) {
        const short* ks = qkv + (base + st * 64 + sr) * 1536 + 512 + h * 64 + sc;
        const short* vs = Vt + ((size_t)(bh * 64 + sr)) * T_ + st * 64 + sc;
        gl_lds16(ks, Kb + w * 512);
        gl_lds16(ks + (size_t)32 * 1536, Kb + 2048 + w * 512);
        gl_lds16(vs, Vb + w * 512);
        gl_lds16(vs + (size_t)32 * T_, Vb + 2048 + w * 512);
    };

    const int rx = c & 7;
    const int ck0 = g ^ rx;              // LDS chunk for source chunk g
    const int ck1 = ck0 ^ 4;             // LDS chunk for source chunk 4+g

    // full tile: QK^T -> exp2 -> l(ones-MFMA) -> PV
    auto tile = [&](const short* Kb, const short* Vb, bool mask_diag) {
        f32x4 s[4];
        __builtin_amdgcn_s_setprio(1);
        #pragma unroll
        for (int mt = 0; mt < 4; mt++) {
            const short* krow = Kb + (mt * 16 + c) * 64;
            bf16x8 k0 = *(const bf16x8*)&krow[ck0 * 8];
            bf16x8 k1 = *(const bf16x8*)&krow[ck1 * 8];
            f32x4 z = __builtin_amdgcn_mfma_f32_16x16x32_bf16(k0, qf0, kZero, 0, 0, 0);
            s[mt] = __builtin_amdgcn_mfma_f32_16x16x32_bf16(k1, qf1, z, 0, 0, 0);
        }
        __builtin_amdgcn_s_setprio(0);

        float p[4][4];
        #pragma unroll
        for (int mt = 0; mt < 4; mt++)
            #pragma unroll
            for (int rr = 0; rr < 4; rr++) {
                float v = s[mt][rr];
                if (mask_diag && (qt * 64 + mt * 16 + 4 * g + rr > qg)) v = -1e30f;
                p[mt][rr] = exp2_f(v);          // exp2(-1e30) -> 0
            }

        bf16x8 pb0, pb1;
        #pragma unroll
        for (int i = 0; i < 8; i++) {
            pb0[i] = f2bf_h(p[(i >> 2)][i & 3]);
            pb1[i] = f2bf_h(p[2 + (i >> 2)][i & 3]);
        }
        __builtin_amdgcn_s_setprio(1);
        // l contribution on the matrix pipe: out[r][c] = sum_k p[k][c]
        lacc = __builtin_amdgcn_mfma_f32_16x16x32_bf16(kOnes, pb0, lacc, 0, 0, 0);
        lacc = __builtin_amdgcn_mfma_f32_16x16x32_bf16(kOnes, pb1, lacc, 0, 0, 0);
        #pragma unroll
        for (int dt = 0; dt < 4; dt++) {
            const short* vrow = Vb + (16 * dt + c) * 64;
            bf16x8 va0 = *(const bf16x8*)&vrow[ck0 * 8];
            bf16x8 va1 = *(const bf16x8*)&vrow[ck1 * 8];
            ot[dt] = __builtin_amdgcn_mfma_f32_16x16x32_bf16(va0, pb0, ot[dt], 0, 0, 0);
            ot[dt] = __builtin_amdgcn_mfma_f32_16x16x32_bf16(va1, pb1, ot[dt], 0, 0, 0);
        }
        __builtin_amdgcn_s_setprio(0);
    };

    short* K0 = sm.s.K[0]; short* K1 = sm.s.K[1];
    short* V0 = sm.s.V[0]; short* V1 = sm.s.V[1];

    stage(K0, V0, 0);
    asm volatile("s_waitcnt vmcnt(0)" ::: "memory");
    __syncthreads();

    int st = 0;
    while (st + 2 <= qt) {              // pairs of common (maskless) tiles
        stage(K1, V1, st + 1);
        tile(K0, V0, false);
        asm volatile("s_waitcnt vmcnt(0)" ::: "memory");
        __syncthreads();
        stage(K0, V0, st + 2);
        tile(K1, V1, false);
        asm volatile("s_waitcnt vmcnt(0)" ::: "memory");
        __syncthreads();
        st += 2;
    }
    if (st < qt) {                      // one common + diagonal in buf1
        stage(K1, V1, st + 1);
        tile(K0, V0, false);
        asm volatile("s_waitcnt vmcnt(0)" ::: "memory");
        __syncthreads();
        tile(K1, V1, true);
    } else {                            // diagonal in buf0
        tile(K0, V0, true);
    }
    __syncthreads();   // all waves done with K/V before union reuse as O

    // epilogue: O^T/l -> LDS transpose.  l = lacc[0] (all regs identical)
    const float inv = 1.0f / lacc[0];
    #pragma unroll
    for (int dt = 0; dt < 4; dt++)
        #pragma unroll
        for (int rr = 0; rr < 4; rr++)
            sm.O[w][c][16 * dt + 4 * g + rr] = ot[dt][rr] * inv;
    // wave-local write->read (per-wave LDS ordering + compiler lgkmcnt)
    const int q = lid >> 2, ch = lid & 3;
    short* dst = y + (base + qt * 64 + w * 16 + q) * 512 + h * 64 + ch * 16;
    short8v o0, o1;
    #pragma unroll
    for (int j = 0; j < 8; j++) o0[j] = f2bf(sm.O[w][q][ch * 16 + j]);
    #pragma unroll
    for (int j = 0; j < 8; j++) o1[j] = f2bf(sm.O[w][q][ch * 16 + 8 + j]);
    *(short8v*)dst = o0;
    *(short8v*)(dst + 8) = o1;
}

// ---------------------------------------------------------------------------
// Orchestration
// ---------------------------------------------------------------------------
extern "C" void kernel_launch(void* const* d_in, const int* in_sizes, int n_in,
                              void* d_out, int out_size, void* d_ws, size_t ws_size,
                              hipStream_t stream) {
    const float* x           = (const float*)d_in[0];
    const float* w_qkv       = (const float*)d_in[1];
    const float* b_qkv       = (const float*)d_in[2];
    const float* w_attn_proj = (const float*)d_in[3];
    const float* b_attn_proj = (const float*)d_in[4];
    const float* w_fc        = (const float*)d_in[5];
    const float* b_fc        = (const float*)d_in[6];
    const float* w_mlp_proj  = (const float*)d_in[7];
    const float* b_mlp_proj  = (const float*)d_in[8];
    const float* ln1_g       = (const float*)d_in[9];
    const float* ln1_b       = (const float*)d_in[10];
    const float* ln2_g       = (const float*)d_in[11];
    const float* ln2_b       = (const float*)d_in[12];

    float* out = (float*)d_out;
    short* ws16 = (short*)d_ws;

    // ws layout (bf16 elems), ~65 MB total
    short* wqkvT = ws16;                                   // [1536][512]
    short* waT   = wqkvT + 1536 * 512;                     // [512][512]
    short* wfcT  = waT   + 512 * 512;                      // [2048][512]
    short* wmT   = wfcT  + 2048 * 512;                     // [512][2048]
    short* xn    = wmT   + 512 * 2048;                     // [8192][512]
    short* ybuf  = xn    + (size_t)BT_ * 512;              // [8192][512]
    short* qkvh  = ybuf  + (size_t)BT_ * 512;              // [8192][2048] (q|k|unused, h)
    short* vtb   = qkvh  + (size_t)BT_ * 2048;             // [2][8][64][4096]

    // 0) weights -> bf16 transposed (single fused launch)
    transpose_w4<<<3072, 256, 0, stream>>>(w_qkv, wqkvT, w_attn_proj, waT,
                                           w_fc, wfcT, w_mlp_proj, wmT);

    // 1) xn1 = LN(x)
    ln_bf16<<<BT_ / 4, 256, 0, stream>>>(x, ln1_g, ln1_b, xn);

    // 2) qkv = xn1 @ w_qkv + b_qkv  (bf16 out; V-region fused into Vt)
    gemm_bf16<0, 1, 0, 1><<<12 * 128, 256, 0, stream>>>(
        xn, wqkvT, b_qkv, nullptr, qkvh, BT_, 1536, 512, 12, 16, vtb);

    // 3) y = attention(qkv, Vt)  (bf16 out) — 1024 blocks, balanced pairing
    attn_mfma<<<1024, 256, 0, stream>>>(qkvh, vtb, ybuf);

    // 4) x2 = x + y @ w_attn_proj + b  (f32 out -> d_out)  GX=4 CY=16
    gemm_bf16<0, 0, 1, 0><<<4 * 128, 256, 0, stream>>>(
        ybuf, waT, b_attn_proj, x, out, BT_, 512, 512, 4, 16, nullptr);

    // 5) xn2 = LN(x2)
    ln_bf16<<<BT_ / 4, 256, 0, stream>>>(out, ln2_g, ln2_b, xn);

    // 6) h = gelu(xn2 @ w_fc + b)  (bf16 out)  GX=16 CY=16
    gemm_bf16<1, 1, 0, 0><<<16 * 128, 256, 0, stream>>>(
        xn, wfcT, b_fc, nullptr, qkvh, BT_, 2048, 512, 16, 16, nullptr);

    // 7) out = x2 + h @ w_mlp_proj + b  (f32 out -> d_out)  GX=4 CY=16
    gemm_bf16<0, 0, 1, 0><<<4 * 128, 256, 0, stream>>>(
        qkvh, wmT, b_mlp_proj, out, out, BT_, 512, 2048, 4, 16, nullptr);
}

// Round 21
// 170.346 us; speedup vs baseline: 1.1134x; 1.0178x over previous
//
#include <hip/hip_runtime.h>
#include <hip/hip_bf16.h>
#include <math.h>

constexpr int B_ = 2;
constexpr int T_ = 4096;
constexpr int C_ = 512;
constexpr int H_ = 8;
constexpr int BT_ = B_ * T_;          // 8192 rows
constexpr float EPS_ = 1e-5f;

typedef __attribute__((ext_vector_type(8))) short bf16x8;   // 8 bf16 (4 VGPRs)
typedef __attribute__((ext_vector_type(4))) short short4v;
typedef __attribute__((ext_vector_type(8))) short short8v;
typedef __attribute__((ext_vector_type(4))) float f32x4;

// fp32 -> bf16 round-to-nearest-even (bit hack, cold paths)
__device__ __forceinline__ short f2bf(float f) {
    unsigned int u = __float_as_uint(f);
    unsigned int r = (u + 0x7fffu + ((u >> 16) & 1u)) >> 16;
    return (short)r;
}
__device__ __forceinline__ float bf2f(short s) {
    return __uint_as_float(((unsigned)(unsigned short)s) << 16);
}
// hot path: compiler fuses adjacent pairs into v_cvt_pk_bf16_f32 (m240)
__device__ __forceinline__ short f2bf_h(float f) {
    union { __hip_bfloat16 h; short s; } u;
    u.h = __float2bfloat16(f);
    return u.s;
}
// raw 2^x (1 inst; hw handles large-negative -> 0)
__device__ __forceinline__ float exp2_f(float x) {
    float r;
    asm("v_exp_f32 %0, %1" : "=v"(r) : "v"(x));
    return r;
}

__device__ __forceinline__ float gelu_f(float v) {
    const float k0 = 0.7978845608028654f;   // sqrt(2/pi)
    const float k1 = 0.044715f;
    return 0.5f * v * (1.0f + tanhf(k0 * (v + k1 * v * v * v)));
}

__device__ __forceinline__ void gl_lds16(const short* gsrc, short* lds) {
    __builtin_amdgcn_global_load_lds(
        (const __attribute__((address_space(1))) void*)gsrc,
        (__attribute__((address_space(3))) void*)lds, 16, 0, 0);
}

// ---------------------------------------------------------------------------
// Fused weight transpose + convert for all 4 weights (one launch).
// ---------------------------------------------------------------------------
__global__ __launch_bounds__(256) void transpose_w4(
    const float* __restrict__ W0, short* __restrict__ D0,   // 512x1536
    const float* __restrict__ W1, short* __restrict__ D1,   // 512x512
    const float* __restrict__ W2, short* __restrict__ D2,   // 512x2048
    const float* __restrict__ W3, short* __restrict__ D3) { // 2048x512
    __shared__ float tile[32][33];
    int bid = blockIdx.x;
    const float* W; short* D; int K, N, nx;
    if (bid < 768)       {             W = W0; D = D0; K = 512;  N = 1536; nx = 48; }
    else if (bid < 1024) { bid -= 768;  W = W1; D = D1; K = 512;  N = 512;  nx = 16; }
    else if (bid < 2048) { bid -= 1024; W = W2; D = D2; K = 512;  N = 2048; nx = 64; }
    else                 { bid -= 2048; W = W3; D = D3; K = 2048; N = 512;  nx = 16; }
    const int n0 = (bid % nx) * 32, k0 = (bid / nx) * 32;
    const int tx = threadIdx.x & 31, ty = threadIdx.x >> 5;   // ty 0..7
    #pragma unroll
    for (int j = 0; j < 4; j++)
        tile[ty + j * 8][tx] = W[(size_t)(k0 + ty + j * 8) * N + n0 + tx];
    __syncthreads();
    #pragma unroll
    for (int j = 0; j < 4; j++)
        D[(size_t)(n0 + ty + j * 8) * K + k0 + tx] = f2bf(tile[tx][ty + j * 8]);
}

// ---------------------------------------------------------------------------
// LayerNorm: 256 threads = 4 waves, one row per wave. fp32 in -> bf16 out.
// ---------------------------------------------------------------------------
__global__ __launch_bounds__(256) void ln_bf16(const float* __restrict__ x,
                                               const float* __restrict__ g,
                                               const float* __restrict__ b,
                                               short* __restrict__ out) {
    const int row = blockIdx.x * 4 + (threadIdx.x >> 6);
    const int lane = threadIdx.x & 63;
    const float* xr = x + (size_t)row * C_;

    float4 v0 = *(const float4*)(xr + lane * 8);
    float4 v1 = *(const float4*)(xr + lane * 8 + 4);

    float s  = v0.x + v0.y + v0.z + v0.w + v1.x + v1.y + v1.z + v1.w;
    float s2 = v0.x*v0.x + v0.y*v0.y + v0.z*v0.z + v0.w*v0.w
             + v1.x*v1.x + v1.y*v1.y + v1.z*v1.z + v1.w*v1.w;
    #pragma unroll
    for (int off = 32; off; off >>= 1) {
        s  += __shfl_down(s, off);
        s2 += __shfl_down(s2, off);
    }
    s  = __shfl(s, 0);
    s2 = __shfl(s2, 0);

    const float mu  = s * (1.0f / C_);
    const float var = s2 * (1.0f / C_) - mu * mu;
    const float rs  = rsqrtf(var + EPS_);

    float4 g0 = *(const float4*)(g + lane * 8);
    float4 g1 = *(const float4*)(g + lane * 8 + 4);
    float4 b0 = *(const float4*)(b + lane * 8);
    float4 b1 = *(const float4*)(b + lane * 8 + 4);

    short8v o;
    o[0] = f2bf((v0.x - mu) * rs * g0.x + b0.x);
    o[1] = f2bf((v0.y - mu) * rs * g0.y + b0.y);
    o[2] = f2bf((v0.z - mu) * rs * g0.z + b0.z);
    o[3] = f2bf((v0.w - mu) * rs * g0.w + b0.w);
    o[4] = f2bf((v1.x - mu) * rs * g1.x + b1.x);
    o[5] = f2bf((v1.y - mu) * rs * g1.y + b1.y);
    o[6] = f2bf((v1.z - mu) * rs * g1.z + b1.z);
    o[7] = f2bf((v1.w - mu) * rs * g1.w + b1.w);
    *(short8v*)(out + (size_t)row * C_ + lane * 8) = o;
}

// ---------------------------------------------------------------------------
// bf16 MFMA GEMM, 64x128x128 tile, SINGLE-buffered (48 KB LDS, 3 blocks/CU).
// r17/r20-proven local optimum. 256B LDS rows, chunk-XOR swizzle.
// VFUSE=1 (qkv GEMM): n0>=1024 tiles write acc directly into Vt with the
// kv-permutation t' = (t&~31)|(8g+4*mt+rr)  (BM=64: t%32 = 16*mt+4g+rr).
// ---------------------------------------------------------------------------
template<int ACT, int OUTBF16, int HASRES, int VFUSE>
__global__ __launch_bounds__(256) void gemm_bf16(const short* __restrict__ A,
                                                 const short* __restrict__ Wt,
                                                 const float* __restrict__ bias,
                                                 const float* __restrict__ res,
                                                 void* __restrict__ outp,
                                                 int M, int N, int K,
                                                 int GX, int CY,
                                                 short* __restrict__ vtb) {
    __shared__ short As[64 * 128];       // 16 KB
    __shared__ short Bs[128 * 128];      // 32 KB

    const int bid = blockIdx.x;
    const int xcd = bid & 7, jb = bid >> 3;
    const int by = xcd * CY + jb / GX;
    const int bx = jb % GX;

    const int t = threadIdx.x;
    const int w = t >> 6;
    const int l = t & 63;
    const int c = l & 15;
    const int g = l >> 4;
    const int wr = w >> 1, wc = w & 1;
    const int m0 = by * 64, n0 = bx * 128;

    const int r16 = t >> 4;
    const int sch = ((t & 15) ^ (r16 & 7)) * 8;       // shorts
    const short* Asrc = A  + (size_t)(m0 + r16) * K + sch;
    const short* Bsrc = Wt + (size_t)(n0 + r16) * K + sch;

    auto stage = [&](int kt) {
        #pragma unroll
        for (int i = 0; i < 4; i++)
            gl_lds16(Asrc + (size_t)(16 * i) * K + kt, &As[i * 2048 + w * 512]);
        #pragma unroll
        for (int i = 0; i < 8; i++)
            gl_lds16(Bsrc + (size_t)(16 * i) * K + kt, &Bs[i * 2048 + w * 512]);
    };

    f32x4 acc[2][4] = {};

    for (int kt = 0; kt < K; kt += 128) {
        stage(kt);
        __syncthreads();     // drains vmcnt (gl_lds) for all waves

        #pragma unroll
        for (int j = 0; j < 4; j++) {     // k-steps of 32 within the 128
            const int ckj = ((4 * j + g) ^ (c & 7)) * 8;   // shorts
            bf16x8 af[2], bfr[4];
            #pragma unroll
            for (int mt = 0; mt < 2; mt++)
                af[mt] = *(const bf16x8*)&As[(wr * 32 + mt * 16 + c) * 128 + ckj];
            #pragma unroll
            for (int nt = 0; nt < 4; nt++)
                bfr[nt] = *(const bf16x8*)&Bs[(wc * 64 + nt * 16 + c) * 128 + ckj];
            #pragma unroll
            for (int mt = 0; mt < 2; mt++)
                #pragma unroll
                for (int nt = 0; nt < 4; nt++)
                    acc[mt][nt] = __builtin_amdgcn_mfma_f32_16x16x32_bf16(
                        af[mt], bfr[nt], acc[mt][nt], 0, 0, 0);
        }

        __syncthreads();     // all reads done before next stage overwrites
    }

    const int colb = n0 + wc * 64;
    float bias_v[4];
    #pragma unroll
    for (int nt = 0; nt < 4; nt++) bias_v[nt] = bias[colb + nt * 16 + c];

    if (VFUSE && n0 >= 1024) {
        // V-fused epilogue: Vt[(b*8+h)*64+d][t'] = bf16(acc + bias)
        const int bq   = m0 >> 12;                 // batch index
        const int trow = (m0 & 4095) + wr * 32;    // t base (&~31 part)
        #pragma unroll
        for (int mt = 0; mt < 2; mt++) {
            const int tb = trow + 8 * g + 4 * mt;
            #pragma unroll
            for (int nt = 0; nt < 4; nt++) {
                const int vcol = colb + nt * 16 + c - 1024;
                const int hh = vcol >> 6, dd = vcol & 63;
                short4v pk;
                #pragma unroll
                for (int rr = 0; rr < 4; rr++)
                    pk[rr] = f2bf(acc[mt][nt][rr] + bias_v[nt]);
                *(short4v*)&vtb[((size_t)((bq * 8 + hh) * 64 + dd)) * T_ + tb] = pk;
            }
        }
        return;
    }

    float* out_f = (float*)outp;
    short* out_h = (short*)outp;

    #pragma unroll
    for (int mt = 0; mt < 2; mt++) {
        #pragma unroll
        for (int rr = 0; rr < 4; rr++) {
            const size_t row = (size_t)(m0 + wr * 32 + mt * 16 + 4 * g + rr);
            #pragma unroll
            for (int nt = 0; nt < 4; nt++) {
                const int col = colb + nt * 16 + c;
                float v = acc[mt][nt][rr] + bias_v[nt];
                if (ACT) v = gelu_f(v);
                if (HASRES) v += res[row * N + col];
                if (OUTBF16) out_h[row * N + col] = f2bf(v);
                else         out_f[row * N + col] = v;
            }
        }
    }
}

// ---------------------------------------------------------------------------
// Flash attention, bf16 MFMA. 512 blocks x 512 threads (8 waves).
// Q-supertile = 128 rows (wave w owns rows Qt*128 + w*16 + c): K/V staged
// ONCE per 128 q-rows -> barriers/CU 130->66, stage issues/thread 4->2.
// Causal: wave-uniform diag tile dw = 2Qt + (w>>2); waves 0-3 skip the
// last kv-tile (barriers still attended). Balance: Qt = lo ? 31-qtr : qtr
// gives every CU exactly {Qt, 31-Qt} -> 66 tiles uniform (r12 model).
// XCD-bijective (b,h) map; fixed-shift softmax; l via ones-MFMA; ping-pong.
// ---------------------------------------------------------------------------
__global__ __launch_bounds__(512) void attn_mfma(const short* __restrict__ qkv,
                                                 const short* __restrict__ Vt,
                                                 short* __restrict__ y) {
    __shared__ union {
        struct { short K[2][64 * 64]; short V[2][64 * 64]; } s;   // 32 KB
        float O[8][16][68];                                       // 34.8 KB
    } sm;

    // bid = xcd + 8*(lo*32 + qtr)
    const int bid = blockIdx.x;
    const int xcd = bid & 7, jj = bid >> 3;
    const int lo = jj >> 5;
    const int qtr = jj & 31;
    const int Qt = lo ? (31 - qtr) : qtr;      // per-CU pair {Qt, 31-Qt}
    const int g16 = xcd * 2 + lo;
    const int b = g16 >> 3, h = g16 & 7;

    const int tid = threadIdx.x, w = tid >> 6, lid = tid & 63;
    const int c = lid & 15, g = lid >> 4;
    const size_t base = (size_t)b * T_;
    const int bh = g16;

    const float qmul = 0.04419417382415922f * 1.4426950408889634f; // 1/sqrt(512)*log2e

    // Q fragment (B operand), pre-scaled; wave w covers q rows Qt*128+w*16+c
    bf16x8 qf0, qf1;
    {
        const short* qa = qkv + (base + Qt * 128 + w * 16 + c) * 1536 + h * 64 + g * 8;
        bf16x8 a0 = *(const bf16x8*)qa;
        bf16x8 a1 = *(const bf16x8*)(qa + 32);
        #pragma unroll
        for (int i = 0; i < 8; i++) {
            qf0[i] = f2bf_h(bf2f(a0[i]) * qmul);
            qf1[i] = f2bf_h(bf2f(a1[i]) * qmul);
        }
    }

    const f32x4 kZero = {0.f, 0.f, 0.f, 0.f};
    bf16x8 kOnes;
    #pragma unroll
    for (int i = 0; i < 8; i++) kOnes[i] = (short)0x3F80;   // bf16 1.0

    f32x4 ot[4] = {};
    f32x4 lacc = {0.f, 0.f, 0.f, 0.f};   // l via ones-MFMA
    const int qg = Qt * 128 + w * 16 + c;
    const int dw = 2 * Qt + (w >> 2);    // this wave's diagonal kv-tile
    const int NT = 2 * Qt + 2;           // kv-tiles to stage (even)

    // staging: 512 threads x 16B cover the full 64x64 K (and V) tile.
    const int sr = tid >> 3;                         // 0..63
    const int sc = ((tid & 7) ^ (sr & 7)) * 8;       // swizzled source chunk

    auto stage = [&](short* Kb, short* Vb, int st) {
        const short* ks = qkv + (base + st * 64 + sr) * 1536 + 512 + h * 64 + sc;
        const short* vs = Vt + ((size_t)(bh * 64 + sr)) * T_ + st * 64 + sc;
        gl_lds16(ks, Kb + w * 512);
        gl_lds16(vs, Vb + w * 512);
    };

    const int rx = c & 7;
    const int ck0 = g ^ rx;              // LDS chunk for source chunk g
    const int ck1 = ck0 ^ 4;             // LDS chunk for source chunk 4+g

    // full tile: QK^T -> exp2 -> l(ones-MFMA) -> PV
    auto tile = [&](const short* Kb, const short* Vb, bool mask_diag) {
        f32x4 s[4];
        __builtin_amdgcn_s_setprio(1);
        #pragma unroll
        for (int mt = 0; mt < 4; mt++) {
            const short* krow = Kb + (mt * 16 + c) * 64;
            bf16x8 k0 = *(const bf16x8*)&krow[ck0 * 8];
            bf16x8 k1 = *(const bf16x8*)&krow[ck1 * 8];
            f32x4 z = __builtin_amdgcn_mfma_f32_16x16x32_bf16(k0, qf0, kZero, 0, 0, 0);
            s[mt] = __builtin_amdgcn_mfma_f32_16x16x32_bf16(k1, qf1, z, 0, 0, 0);
        }
        __builtin_amdgcn_s_setprio(0);

        float p[4][4];
        #pragma unroll
        for (int mt = 0; mt < 4; mt++)
            #pragma unroll
            for (int rr = 0; rr < 4; rr++) {
                float v = s[mt][rr];
                if (mask_diag && (dw * 64 + mt * 16 + 4 * g + rr > qg)) v = -1e30f;
                p[mt][rr] = exp2_f(v);          // exp2(-1e30) -> 0
            }

        bf16x8 pb0, pb1;
        #pragma unroll
        for (int i = 0; i < 8; i++) {
            pb0[i] = f2bf_h(p[(i >> 2)][i & 3]);
            pb1[i] = f2bf_h(p[2 + (i >> 2)][i & 3]);
        }
        __builtin_amdgcn_s_setprio(1);
        // l contribution on the matrix pipe: out[r][c] = sum_k p[k][c]
        lacc = __builtin_amdgcn_mfma_f32_16x16x32_bf16(kOnes, pb0, lacc, 0, 0, 0);
        lacc = __builtin_amdgcn_mfma_f32_16x16x32_bf16(kOnes, pb1, lacc, 0, 0, 0);
        #pragma unroll
        for (int dt = 0; dt < 4; dt++) {
            const short* vrow = Vb + (16 * dt + c) * 64;
            bf16x8 va0 = *(const bf16x8*)&vrow[ck0 * 8];
            bf16x8 va1 = *(const bf16x8*)&vrow[ck1 * 8];
            ot[dt] = __builtin_amdgcn_mfma_f32_16x16x32_bf16(va0, pb0, ot[dt], 0, 0, 0);
            ot[dt] = __builtin_amdgcn_mfma_f32_16x16x32_bf16(va1, pb1, ot[dt], 0, 0, 0);
        }
        __builtin_amdgcn_s_setprio(0);
    };

    short* K0 = sm.s.K[0]; short* K1 = sm.s.K[1];
    short* V0 = sm.s.V[0]; short* V1 = sm.s.V[1];

    stage(K0, V0, 0);
    asm volatile("s_waitcnt vmcnt(0)" ::: "memory");
    __syncthreads();

    // NT is even: clean pairs. Waves with dw < st skip compute (uniform branch)
    int st = 0;
    while (st + 2 <= NT) {
        if (st + 1 < NT) stage(K1, V1, st + 1);
        if (st <= dw) tile(K0, V0, st == dw);
        asm volatile("s_waitcnt vmcnt(0)" ::: "memory");
        __syncthreads();
        if (st + 2 < NT) stage(K0, V0, st + 2);
        if (st + 1 <= dw) tile(K1, V1, st + 1 == dw);
        asm volatile("s_waitcnt vmcnt(0)" ::: "memory");
        __syncthreads();
        st += 2;
    }

    // epilogue: O^T/l -> LDS transpose.  l = lacc[0] (all regs identical)
    const float inv = 1.0f / lacc[0];
    #pragma unroll
    for (int dt = 0; dt < 4; dt++)
        #pragma unroll
        for (int rr = 0; rr < 4; rr++)
            sm.O[w][c][16 * dt + 4 * g + rr] = ot[dt][rr] * inv;
    // wave-local write->read (per-wave LDS ordering + compiler lgkmcnt)
    const int q = lid >> 2, ch = lid & 3;
    short* dst = y + (base + Qt * 128 + w * 16 + q) * 512 + h * 64 + ch * 16;
    short8v o0, o1;
    #pragma unroll
    for (int j = 0; j < 8; j++) o0[j] = f2bf(sm.O[w][q][ch * 16 + j]);
    #pragma unroll
    for (int j = 0; j < 8; j++) o1[j] = f2bf(sm.O[w][q][ch * 16 + 8 + j]);
    *(short8v*)dst = o0;
    *(short8v*)(dst + 8) = o1;
}

// ---------------------------------------------------------------------------
// Orchestration
// ---------------------------------------------------------------------------
extern "C" void kernel_launch(void* const* d_in, const int* in_sizes, int n_in,
                              void* d_out, int out_size, void* d_ws, size_t ws_size,
                              hipStream_t stream) {
    const float* x           = (const float*)d_in[0];
    const float* w_qkv       = (const float*)d_in[1];
    const float* b_qkv       = (const float*)d_in[2];
    const float* w_attn_proj = (const float*)d_in[3];
    const float* b_attn_proj = (const float*)d_in[4];
    const float* w_fc        = (const float*)d_in[5];
    const float* b_fc        = (const float*)d_in[6];
    const float* w_mlp_proj  = (const float*)d_in[7];
    const float* b_mlp_proj  = (const float*)d_in[8];
    const float* ln1_g       = (const float*)d_in[9];
    const float* ln1_b       = (const float*)d_in[10];
    const float* ln2_g       = (const float*)d_in[11];
    const float* ln2_b       = (const float*)d_in[12];

    float* out = (float*)d_out;
    short* ws16 = (short*)d_ws;

    // ws layout (bf16 elems), ~65 MB total
    short* wqkvT = ws16;                                   // [1536][512]
    short* waT   = wqkvT + 1536 * 512;                     // [512][512]
    short* wfcT  = waT   + 512 * 512;                      // [2048][512]
    short* wmT   = wfcT  + 2048 * 512;                     // [512][2048]
    short* xn    = wmT   + 512 * 2048;                     // [8192][512]
    short* ybuf  = xn    + (size_t)BT_ * 512;              // [8192][512]
    short* qkvh  = ybuf  + (size_t)BT_ * 512;              // [8192][2048] (q|k|unused, h)
    short* vtb   = qkvh  + (size_t)BT_ * 2048;             // [2][8][64][4096]

    // 0) weights -> bf16 transposed (single fused launch)
    transpose_w4<<<3072, 256, 0, stream>>>(w_qkv, wqkvT, w_attn_proj, waT,
                                           w_fc, wfcT, w_mlp_proj, wmT);

    // 1) xn1 = LN(x)
    ln_bf16<<<BT_ / 4, 256, 0, stream>>>(x, ln1_g, ln1_b, xn);

    // 2) qkv = xn1 @ w_qkv + b_qkv  (bf16 out; V-region fused into Vt)
    gemm_bf16<0, 1, 0, 1><<<12 * 128, 256, 0, stream>>>(
        xn, wqkvT, b_qkv, nullptr, qkvh, BT_, 1536, 512, 12, 16, vtb);

    // 3) y = attention(qkv, Vt)  (bf16 out) — 512 blocks x 8 waves
    attn_mfma<<<512, 512, 0, stream>>>(qkvh, vtb, ybuf);

    // 4) x2 = x + y @ w_attn_proj + b  (f32 out -> d_out)  GX=4 CY=16
    gemm_bf16<0, 0, 1, 0><<<4 * 128, 256, 0, stream>>>(
        ybuf, waT, b_attn_proj, x, out, BT_, 512, 512, 4, 16, nullptr);

    // 5) xn2 = LN(x2)
    ln_bf16<<<BT_ / 4, 256, 0, stream>>>(out, ln2_g, ln2_b, xn);

    // 6) h = gelu(xn2 @ w_fc + b)  (bf16 out)  GX=16 CY=16
    gemm_bf16<1, 1, 0, 0><<<16 * 128, 256, 0, stream>>>(
        xn, wfcT, b_fc, nullptr, qkvh, BT_, 2048, 512, 16, 16, nullptr);

    // 7) out = x2 + h @ w_mlp_proj + b  (f32 out -> d_out)  GX=4 CY=16
    gemm_bf16<0, 0, 1, 0><<<4 * 128, 256, 0, stream>>>(
        qkvh, wmT, b_mlp_proj, out, out, BT_, 512, 2048, 4, 16, nullptr);
}

// Round 22
// 167.415 us; speedup vs baseline: 1.1329x; 1.0175x over previous
//
#include <hip/hip_runtime.h>
#include <hip/hip_bf16.h>
#include <math.h>

constexpr int B_ = 2;
constexpr int T_ = 4096;
constexpr int C_ = 512;
constexpr int H_ = 8;
constexpr int BT_ = B_ * T_;          // 8192 rows
constexpr float EPS_ = 1e-5f;

typedef __attribute__((ext_vector_type(8))) short bf16x8;   // 8 bf16 (4 VGPRs)
typedef __attribute__((ext_vector_type(4))) short short4v;
typedef __attribute__((ext_vector_type(8))) short short8v;
typedef __attribute__((ext_vector_type(4))) float f32x4;

// fp32 -> bf16 round-to-nearest-even (bit hack, cold paths)
__device__ __forceinline__ short f2bf(float f) {
    unsigned int u = __float_as_uint(f);
    unsigned int r = (u + 0x7fffu + ((u >> 16) & 1u)) >> 16;
    return (short)r;
}
__device__ __forceinline__ float bf2f(short s) {
    return __uint_as_float(((unsigned)(unsigned short)s) << 16);
}
// hot path: compiler fuses adjacent pairs into v_cvt_pk_bf16_f32 (m240)
__device__ __forceinline__ short f2bf_h(float f) {
    union { __hip_bfloat16 h; short s; } u;
    u.h = __float2bfloat16(f);
    return u.s;
}
// raw 2^x (1 inst; hw handles large-negative -> 0)
__device__ __forceinline__ float exp2_f(float x) {
    float r;
    asm("v_exp_f32 %0, %1" : "=v"(r) : "v"(x));
    return r;
}

__device__ __forceinline__ float gelu_f(float v) {
    const float k0 = 0.7978845608028654f;   // sqrt(2/pi)
    const float k1 = 0.044715f;
    return 0.5f * v * (1.0f + tanhf(k0 * (v + k1 * v * v * v)));
}

__device__ __forceinline__ void gl_lds16(const short* gsrc, short* lds) {
    __builtin_amdgcn_global_load_lds(
        (const __attribute__((address_space(1))) void*)gsrc,
        (__attribute__((address_space(3))) void*)lds, 16, 0, 0);
}

// ---------------------------------------------------------------------------
// Fused prep: blocks 0..3071 transpose+convert all 4 weights;
// blocks 3072..5119 LayerNorm1 (x -> xn, bf16). Independent streams overlap.
// ---------------------------------------------------------------------------
__global__ __launch_bounds__(256) void prep_fused(
    const float* __restrict__ W0, short* __restrict__ D0,   // 512x1536
    const float* __restrict__ W1, short* __restrict__ D1,   // 512x512
    const float* __restrict__ W2, short* __restrict__ D2,   // 512x2048
    const float* __restrict__ W3, short* __restrict__ D3,   // 2048x512
    const float* __restrict__ x,  const float* __restrict__ lng,
    const float* __restrict__ lnb, short* __restrict__ xout) {
    __shared__ float tile[32][33];
    int bid = blockIdx.x;

    if (bid >= 3072) {
        // ---- LN path: 4 rows per block, one wave per row ----
        const int row = (bid - 3072) * 4 + (threadIdx.x >> 6);
        const int lane = threadIdx.x & 63;
        const float* xr = x + (size_t)row * C_;

        float4 v0 = *(const float4*)(xr + lane * 8);
        float4 v1 = *(const float4*)(xr + lane * 8 + 4);

        float s  = v0.x + v0.y + v0.z + v0.w + v1.x + v1.y + v1.z + v1.w;
        float s2 = v0.x*v0.x + v0.y*v0.y + v0.z*v0.z + v0.w*v0.w
                 + v1.x*v1.x + v1.y*v1.y + v1.z*v1.z + v1.w*v1.w;
        #pragma unroll
        for (int off = 32; off; off >>= 1) {
            s  += __shfl_down(s, off);
            s2 += __shfl_down(s2, off);
        }
        s  = __shfl(s, 0);
        s2 = __shfl(s2, 0);

        const float mu  = s * (1.0f / C_);
        const float var = s2 * (1.0f / C_) - mu * mu;
        const float rs  = rsqrtf(var + EPS_);

        float4 g0 = *(const float4*)(lng + lane * 8);
        float4 g1 = *(const float4*)(lng + lane * 8 + 4);
        float4 b0 = *(const float4*)(lnb + lane * 8);
        float4 b1 = *(const float4*)(lnb + lane * 8 + 4);

        short8v o;
        o[0] = f2bf((v0.x - mu) * rs * g0.x + b0.x);
        o[1] = f2bf((v0.y - mu) * rs * g0.y + b0.y);
        o[2] = f2bf((v0.z - mu) * rs * g0.z + b0.z);
        o[3] = f2bf((v0.w - mu) * rs * g0.w + b0.w);
        o[4] = f2bf((v1.x - mu) * rs * g1.x + b1.x);
        o[5] = f2bf((v1.y - mu) * rs * g1.y + b1.y);
        o[6] = f2bf((v1.z - mu) * rs * g1.z + b1.z);
        o[7] = f2bf((v1.w - mu) * rs * g1.w + b1.w);
        *(short8v*)(xout + (size_t)row * C_ + lane * 8) = o;
        return;
    }

    // ---- weight transpose path (identical to transpose_w4) ----
    const float* W; short* D; int K, N, nx;
    if (bid < 768)       {             W = W0; D = D0; K = 512;  N = 1536; nx = 48; }
    else if (bid < 1024) { bid -= 768;  W = W1; D = D1; K = 512;  N = 512;  nx = 16; }
    else if (bid < 2048) { bid -= 1024; W = W2; D = D2; K = 512;  N = 2048; nx = 64; }
    else                 { bid -= 2048; W = W3; D = D3; K = 2048; N = 512;  nx = 16; }
    const int n0 = (bid % nx) * 32, k0 = (bid / nx) * 32;
    const int tx = threadIdx.x & 31, ty = threadIdx.x >> 5;   // ty 0..7
    #pragma unroll
    for (int j = 0; j < 4; j++)
        tile[ty + j * 8][tx] = W[(size_t)(k0 + ty + j * 8) * N + n0 + tx];
    __syncthreads();
    #pragma unroll
    for (int j = 0; j < 4; j++)
        D[(size_t)(n0 + ty + j * 8) * K + k0 + tx] = f2bf(tile[tx][ty + j * 8]);
}

// ---------------------------------------------------------------------------
// LayerNorm: 256 threads = 4 waves, one row per wave. fp32 in -> bf16 out.
// ---------------------------------------------------------------------------
__global__ __launch_bounds__(256) void ln_bf16(const float* __restrict__ x,
                                               const float* __restrict__ g,
                                               const float* __restrict__ b,
                                               short* __restrict__ out) {
    const int row = blockIdx.x * 4 + (threadIdx.x >> 6);
    const int lane = threadIdx.x & 63;
    const float* xr = x + (size_t)row * C_;

    float4 v0 = *(const float4*)(xr + lane * 8);
    float4 v1 = *(const float4*)(xr + lane * 8 + 4);

    float s  = v0.x + v0.y + v0.z + v0.w + v1.x + v1.y + v1.z + v1.w;
    float s2 = v0.x*v0.x + v0.y*v0.y + v0.z*v0.z + v0.w*v0.w
             + v1.x*v1.x + v1.y*v1.y + v1.z*v1.z + v1.w*v1.w;
    #pragma unroll
    for (int off = 32; off; off >>= 1) {
        s  += __shfl_down(s, off);
        s2 += __shfl_down(s2, off);
    }
    s  = __shfl(s, 0);
    s2 = __shfl(s2, 0);

    const float mu  = s * (1.0f / C_);
    const float var = s2 * (1.0f / C_) - mu * mu;
    const float rs  = rsqrtf(var + EPS_);

    float4 g0 = *(const float4*)(g + lane * 8);
    float4 g1 = *(const float4*)(g + lane * 8 + 4);
    float4 b0 = *(const float4*)(b + lane * 8);
    float4 b1 = *(const float4*)(b + lane * 8 + 4);

    short8v o;
    o[0] = f2bf((v0.x - mu) * rs * g0.x + b0.x);
    o[1] = f2bf((v0.y - mu) * rs * g0.y + b0.y);
    o[2] = f2bf((v0.z - mu) * rs * g0.z + b0.z);
    o[3] = f2bf((v0.w - mu) * rs * g0.w + b0.w);
    o[4] = f2bf((v1.x - mu) * rs * g1.x + b1.x);
    o[5] = f2bf((v1.y - mu) * rs * g1.y + b1.y);
    o[6] = f2bf((v1.z - mu) * rs * g1.z + b1.z);
    o[7] = f2bf((v1.w - mu) * rs * g1.w + b1.w);
    *(short8v*)(out + (size_t)row * C_ + lane * 8) = o;
}

// ---------------------------------------------------------------------------
// bf16 MFMA GEMM, 64x128x128 tile, SINGLE-buffered (48 KB LDS, 3 blocks/CU).
// r17/r20-proven local optimum. 256B LDS rows, chunk-XOR swizzle.
// VFUSE=1 (qkv GEMM): n0>=1024 tiles write acc directly into Vt with the
// kv-permutation t' = (t&~31)|(8g+4*mt+rr)  (BM=64: t%32 = 16*mt+4g+rr).
// ---------------------------------------------------------------------------
template<int ACT, int OUTBF16, int HASRES, int VFUSE>
__global__ __launch_bounds__(256) void gemm_bf16(const short* __restrict__ A,
                                                 const short* __restrict__ Wt,
                                                 const float* __restrict__ bias,
                                                 const float* __restrict__ res,
                                                 void* __restrict__ outp,
                                                 int M, int N, int K,
                                                 int GX, int CY,
                                                 short* __restrict__ vtb) {
    __shared__ short As[64 * 128];       // 16 KB
    __shared__ short Bs[128 * 128];      // 32 KB

    const int bid = blockIdx.x;
    const int xcd = bid & 7, jb = bid >> 3;
    const int by = xcd * CY + jb / GX;
    const int bx = jb % GX;

    const int t = threadIdx.x;
    const int w = t >> 6;
    const int l = t & 63;
    const int c = l & 15;
    const int g = l >> 4;
    const int wr = w >> 1, wc = w & 1;
    const int m0 = by * 64, n0 = bx * 128;

    const int r16 = t >> 4;
    const int sch = ((t & 15) ^ (r16 & 7)) * 8;       // shorts
    const short* Asrc = A  + (size_t)(m0 + r16) * K + sch;
    const short* Bsrc = Wt + (size_t)(n0 + r16) * K + sch;

    auto stage = [&](int kt) {
        #pragma unroll
        for (int i = 0; i < 4; i++)
            gl_lds16(Asrc + (size_t)(16 * i) * K + kt, &As[i * 2048 + w * 512]);
        #pragma unroll
        for (int i = 0; i < 8; i++)
            gl_lds16(Bsrc + (size_t)(16 * i) * K + kt, &Bs[i * 2048 + w * 512]);
    };

    f32x4 acc[2][4] = {};

    for (int kt = 0; kt < K; kt += 128) {
        stage(kt);
        __syncthreads();     // drains vmcnt (gl_lds) for all waves

        #pragma unroll
        for (int j = 0; j < 4; j++) {     // k-steps of 32 within the 128
            const int ckj = ((4 * j + g) ^ (c & 7)) * 8;   // shorts
            bf16x8 af[2], bfr[4];
            #pragma unroll
            for (int mt = 0; mt < 2; mt++)
                af[mt] = *(const bf16x8*)&As[(wr * 32 + mt * 16 + c) * 128 + ckj];
            #pragma unroll
            for (int nt = 0; nt < 4; nt++)
                bfr[nt] = *(const bf16x8*)&Bs[(wc * 64 + nt * 16 + c) * 128 + ckj];
            #pragma unroll
            for (int mt = 0; mt < 2; mt++)
                #pragma unroll
                for (int nt = 0; nt < 4; nt++)
                    acc[mt][nt] = __builtin_amdgcn_mfma_f32_16x16x32_bf16(
                        af[mt], bfr[nt], acc[mt][nt], 0, 0, 0);
        }

        __syncthreads();     // all reads done before next stage overwrites
    }

    const int colb = n0 + wc * 64;
    float bias_v[4];
    #pragma unroll
    for (int nt = 0; nt < 4; nt++) bias_v[nt] = bias[colb + nt * 16 + c];

    if (VFUSE && n0 >= 1024) {
        // V-fused epilogue: Vt[(b*8+h)*64+d][t'] = bf16(acc + bias)
        const int bq   = m0 >> 12;                 // batch index
        const int trow = (m0 & 4095) + wr * 32;    // t base (&~31 part)
        #pragma unroll
        for (int mt = 0; mt < 2; mt++) {
            const int tb = trow + 8 * g + 4 * mt;
            #pragma unroll
            for (int nt = 0; nt < 4; nt++) {
                const int vcol = colb + nt * 16 + c - 1024;
                const int hh = vcol >> 6, dd = vcol & 63;
                short4v pk;
                #pragma unroll
                for (int rr = 0; rr < 4; rr++)
                    pk[rr] = f2bf(acc[mt][nt][rr] + bias_v[nt]);
                *(short4v*)&vtb[((size_t)((bq * 8 + hh) * 64 + dd)) * T_ + tb] = pk;
            }
        }
        return;
    }

    float* out_f = (float*)outp;
    short* out_h = (short*)outp;

    #pragma unroll
    for (int mt = 0; mt < 2; mt++) {
        #pragma unroll
        for (int rr = 0; rr < 4; rr++) {
            const size_t row = (size_t)(m0 + wr * 32 + mt * 16 + 4 * g + rr);
            #pragma unroll
            for (int nt = 0; nt < 4; nt++) {
                const int col = colb + nt * 16 + c;
                float v = acc[mt][nt][rr] + bias_v[nt];
                if (ACT) v = gelu_f(v);
                if (HASRES) v += res[row * N + col];
                if (OUTBF16) out_h[row * N + col] = f2bf(v);
                else         out_f[row * N + col] = v;
            }
        }
    }
}

// ---------------------------------------------------------------------------
// Flash attention, bf16 MFMA. 512 blocks x 512 threads (8 waves).
// Q-supertile = 128 rows; K/V staged once per supertile; causal via
// wave-uniform diag tile dw = 2Qt + (w>>2). Balance Qt = lo ? 31-qtr : qtr.
// XCD-bijective (b,h) map; fixed-shift softmax; l via ones-MFMA; ping-pong.
// (r21-measured 56.6 us — attn floor for this structure.)
// ---------------------------------------------------------------------------
__global__ __launch_bounds__(512) void attn_mfma(const short* __restrict__ qkv,
                                                 const short* __restrict__ Vt,
                                                 short* __restrict__ y) {
    __shared__ union {
        struct { short K[2][64 * 64]; short V[2][64 * 64]; } s;   // 32 KB
        float O[8][16][68];                                       // 34.8 KB
    } sm;

    // bid = xcd + 8*(lo*32 + qtr)
    const int bid = blockIdx.x;
    const int xcd = bid & 7, jj = bid >> 3;
    const int lo = jj >> 5;
    const int qtr = jj & 31;
    const int Qt = lo ? (31 - qtr) : qtr;      // per-CU pair {Qt, 31-Qt}
    const int g16 = xcd * 2 + lo;
    const int b = g16 >> 3, h = g16 & 7;

    const int tid = threadIdx.x, w = tid >> 6, lid = tid & 63;
    const int c = lid & 15, g = lid >> 4;
    const size_t base = (size_t)b * T_;
    const int bh = g16;

    const float qmul = 0.04419417382415922f * 1.4426950408889634f; // 1/sqrt(512)*log2e

    // Q fragment (B operand), pre-scaled; wave w covers q rows Qt*128+w*16+c
    bf16x8 qf0, qf1;
    {
        const short* qa = qkv + (base + Qt * 128 + w * 16 + c) * 1536 + h * 64 + g * 8;
        bf16x8 a0 = *(const bf16x8*)qa;
        bf16x8 a1 = *(const bf16x8*)(qa + 32);
        #pragma unroll
        for (int i = 0; i < 8; i++) {
            qf0[i] = f2bf_h(bf2f(a0[i]) * qmul);
            qf1[i] = f2bf_h(bf2f(a1[i]) * qmul);
        }
    }

    const f32x4 kZero = {0.f, 0.f, 0.f, 0.f};
    bf16x8 kOnes;
    #pragma unroll
    for (int i = 0; i < 8; i++) kOnes[i] = (short)0x3F80;   // bf16 1.0

    f32x4 ot[4] = {};
    f32x4 lacc = {0.f, 0.f, 0.f, 0.f};   // l via ones-MFMA
    const int qg = Qt * 128 + w * 16 + c;
    const int dw = 2 * Qt + (w >> 2);    // this wave's diagonal kv-tile
    const int NT = 2 * Qt + 2;           // kv-tiles to stage (even)

    // staging: 512 threads x 16B cover the full 64x64 K (and V) tile.
    const int sr = tid >> 3;                         // 0..63
    const int sc = ((tid & 7) ^ (sr & 7)) * 8;       // swizzled source chunk

    auto stage = [&](short* Kb, short* Vb, int st) {
        const short* ks = qkv + (base + st * 64 + sr) * 1536 + 512 + h * 64 + sc;
        const short* vs = Vt + ((size_t)(bh * 64 + sr)) * T_ + st * 64 + sc;
        gl_lds16(ks, Kb + w * 512);
        gl_lds16(vs, Vb + w * 512);
    };

    const int rx = c & 7;
    const int ck0 = g ^ rx;              // LDS chunk for source chunk g
    const int ck1 = ck0 ^ 4;             // LDS chunk for source chunk 4+g

    // full tile: QK^T -> exp2 -> l(ones-MFMA) -> PV
    auto tile = [&](const short* Kb, const short* Vb, bool mask_diag) {
        f32x4 s[4];
        __builtin_amdgcn_s_setprio(1);
        #pragma unroll
        for (int mt = 0; mt < 4; mt++) {
            const short* krow = Kb + (mt * 16 + c) * 64;
            bf16x8 k0 = *(const bf16x8*)&krow[ck0 * 8];
            bf16x8 k1 = *(const bf16x8*)&krow[ck1 * 8];
            f32x4 z = __builtin_amdgcn_mfma_f32_16x16x32_bf16(k0, qf0, kZero, 0, 0, 0);
            s[mt] = __builtin_amdgcn_mfma_f32_16x16x32_bf16(k1, qf1, z, 0, 0, 0);
        }
        __builtin_amdgcn_s_setprio(0);

        float p[4][4];
        #pragma unroll
        for (int mt = 0; mt < 4; mt++)
            #pragma unroll
            for (int rr = 0; rr < 4; rr++) {
                float v = s[mt][rr];
                if (mask_diag && (dw * 64 + mt * 16 + 4 * g + rr > qg)) v = -1e30f;
                p[mt][rr] = exp2_f(v);          // exp2(-1e30) -> 0
            }

        bf16x8 pb0, pb1;
        #pragma unroll
        for (int i = 0; i < 8; i++) {
            pb0[i] = f2bf_h(p[(i >> 2)][i & 3]);
            pb1[i] = f2bf_h(p[2 + (i >> 2)][i & 3]);
        }
        __builtin_amdgcn_s_setprio(1);
        // l contribution on the matrix pipe: out[r][c] = sum_k p[k][c]
        lacc = __builtin_amdgcn_mfma_f32_16x16x32_bf16(kOnes, pb0, lacc, 0, 0, 0);
        lacc = __builtin_amdgcn_mfma_f32_16x16x32_bf16(kOnes, pb1, lacc, 0, 0, 0);
        #pragma unroll
        for (int dt = 0; dt < 4; dt++) {
            const short* vrow = Vb + (16 * dt + c) * 64;
            bf16x8 va0 = *(const bf16x8*)&vrow[ck0 * 8];
            bf16x8 va1 = *(const bf16x8*)&vrow[ck1 * 8];
            ot[dt] = __builtin_amdgcn_mfma_f32_16x16x32_bf16(va0, pb0, ot[dt], 0, 0, 0);
            ot[dt] = __builtin_amdgcn_mfma_f32_16x16x32_bf16(va1, pb1, ot[dt], 0, 0, 0);
        }
        __builtin_amdgcn_s_setprio(0);
    };

    short* K0 = sm.s.K[0]; short* K1 = sm.s.K[1];
    short* V0 = sm.s.V[0]; short* V1 = sm.s.V[1];

    stage(K0, V0, 0);
    asm volatile("s_waitcnt vmcnt(0)" ::: "memory");
    __syncthreads();

    // NT is even: clean pairs. Waves with dw < st skip compute (uniform branch)
    int st = 0;
    while (st + 2 <= NT) {
        if (st + 1 < NT) stage(K1, V1, st + 1);
        if (st <= dw) tile(K0, V0, st == dw);
        asm volatile("s_waitcnt vmcnt(0)" ::: "memory");
        __syncthreads();
        if (st + 2 < NT) stage(K0, V0, st + 2);
        if (st + 1 <= dw) tile(K1, V1, st + 1 == dw);
        asm volatile("s_waitcnt vmcnt(0)" ::: "memory");
        __syncthreads();
        st += 2;
    }

    // epilogue: O^T/l -> LDS transpose.  l = lacc[0] (all regs identical)
    const float inv = 1.0f / lacc[0];
    #pragma unroll
    for (int dt = 0; dt < 4; dt++)
        #pragma unroll
        for (int rr = 0; rr < 4; rr++)
            sm.O[w][c][16 * dt + 4 * g + rr] = ot[dt][rr] * inv;
    // wave-local write->read (per-wave LDS ordering + compiler lgkmcnt)
    const int q = lid >> 2, ch = lid & 3;
    short* dst = y + (base + Qt * 128 + w * 16 + q) * 512 + h * 64 + ch * 16;
    short8v o0, o1;
    #pragma unroll
    for (int j = 0; j < 8; j++) o0[j] = f2bf(sm.O[w][q][ch * 16 + j]);
    #pragma unroll
    for (int j = 0; j < 8; j++) o1[j] = f2bf(sm.O[w][q][ch * 16 + 8 + j]);
    *(short8v*)dst = o0;
    *(short8v*)(dst + 8) = o1;
}

// ---------------------------------------------------------------------------
// Orchestration
// ---------------------------------------------------------------------------
extern "C" void kernel_launch(void* const* d_in, const int* in_sizes, int n_in,
                              void* d_out, int out_size, void* d_ws, size_t ws_size,
                              hipStream_t stream) {
    const float* x           = (const float*)d_in[0];
    const float* w_qkv       = (const float*)d_in[1];
    const float* b_qkv       = (const float*)d_in[2];
    const float* w_attn_proj = (const float*)d_in[3];
    const float* b_attn_proj = (const float*)d_in[4];
    const float* w_fc        = (const float*)d_in[5];
    const float* b_fc        = (const float*)d_in[6];
    const float* w_mlp_proj  = (const float*)d_in[7];
    const float* b_mlp_proj  = (const float*)d_in[8];
    const float* ln1_g       = (const float*)d_in[9];
    const float* ln1_b       = (const float*)d_in[10];
    const float* ln2_g       = (const float*)d_in[11];
    const float* ln2_b       = (const float*)d_in[12];

    float* out = (float*)d_out;
    short* ws16 = (short*)d_ws;

    // ws layout (bf16 elems), ~65 MB total
    short* wqkvT = ws16;                                   // [1536][512]
    short* waT   = wqkvT + 1536 * 512;                     // [512][512]
    short* wfcT  = waT   + 512 * 512;                      // [2048][512]
    short* wmT   = wfcT  + 2048 * 512;                     // [512][2048]
    short* xn    = wmT   + 512 * 2048;                     // [8192][512]
    short* ybuf  = xn    + (size_t)BT_ * 512;              // [8192][512]
    short* qkvh  = ybuf  + (size_t)BT_ * 512;              // [8192][2048] (q|k|unused, h)
    short* vtb   = qkvh  + (size_t)BT_ * 2048;             // [2][8][64][4096]

    // 0+1) weights -> bf16 transposed AND xn1 = LN(x), one fused launch
    prep_fused<<<3072 + BT_ / 4, 256, 0, stream>>>(
        w_qkv, wqkvT, w_attn_proj, waT, w_fc, wfcT, w_mlp_proj, wmT,
        x, ln1_g, ln1_b, xn);

    // 2) qkv = xn1 @ w_qkv + b_qkv  (bf16 out; V-region fused into Vt)
    gemm_bf16<0, 1, 0, 1><<<12 * 128, 256, 0, stream>>>(
        xn, wqkvT, b_qkv, nullptr, qkvh, BT_, 1536, 512, 12, 16, vtb);

    // 3) y = attention(qkv, Vt)  (bf16 out) — 512 blocks x 8 waves
    attn_mfma<<<512, 512, 0, stream>>>(qkvh, vtb, ybuf);

    // 4) x2 = x + y @ w_attn_proj + b  (f32 out -> d_out)  GX=4 CY=16
    gemm_bf16<0, 0, 1, 0><<<4 * 128, 256, 0, stream>>>(
        ybuf, waT, b_attn_proj, x, out, BT_, 512, 512, 4, 16, nullptr);

    // 5) xn2 = LN(x2)
    ln_bf16<<<BT_ / 4, 256, 0, stream>>>(out, ln2_g, ln2_b, xn);

    // 6) h = gelu(xn2 @ w_fc + b)  (bf16 out)  GX=16 CY=16
    gemm_bf16<1, 1, 0, 0><<<16 * 128, 256, 0, stream>>>(
        xn, wfcT, b_fc, nullptr, qkvh, BT_, 2048, 512, 16, 16, nullptr);

    // 7) out = x2 + h @ w_mlp_proj + b  (f32 out -> d_out)  GX=4 CY=16
    gemm_bf16<0, 0, 1, 0><<<4 * 128, 256, 0, stream>>>(
        qkvh, wmT, b_mlp_proj, out, out, BT_, 512, 2048, 4, 16, nullptr);
}

// Round 23
// 158.462 us; speedup vs baseline: 1.1969x; 1.0565x over previous
//
#include <hip/hip_runtime.h>
#include <hip/hip_bf16.h>
#include <math.h>

constexpr int B_ = 2;
constexpr int T_ = 4096;
constexpr int C_ = 512;
constexpr int H_ = 8;
constexpr int BT_ = B_ * T_;          // 8192 rows
constexpr float EPS_ = 1e-5f;

typedef __attribute__((ext_vector_type(8))) short bf16x8;   // 8 bf16 (4 VGPRs)
typedef __attribute__((ext_vector_type(4))) short short4v;
typedef __attribute__((ext_vector_type(8))) short short8v;
typedef __attribute__((ext_vector_type(4))) float f32x4;

// fp32 -> bf16 round-to-nearest-even (bit hack, cold paths)
__device__ __forceinline__ short f2bf(float f) {
    unsigned int u = __float_as_uint(f);
    unsigned int r = (u + 0x7fffu + ((u >> 16) & 1u)) >> 16;
    return (short)r;
}
__device__ __forceinline__ float bf2f(short s) {
    return __uint_as_float(((unsigned)(unsigned short)s) << 16);
}
// hot path: compiler fuses adjacent pairs into v_cvt_pk_bf16_f32 (m240)
__device__ __forceinline__ short f2bf_h(float f) {
    union { __hip_bfloat16 h; short s; } u;
    u.h = __float2bfloat16(f);
    return u.s;
}
// raw 2^x (1 inst; hw handles large-negative -> 0)
__device__ __forceinline__ float exp2_f(float x) {
    float r;
    asm("v_exp_f32 %0, %1" : "=v"(r) : "v"(x));
    return r;
}

// tanh-GELU via identity 0.5v(1+tanh(z)) = v/(1+e^{-2z}); ~7 VALU ops.
__device__ __forceinline__ float gelu_f(float v) {
    const float k0 = 0.7978845608028654f;   // sqrt(2/pi)
    const float k1 = 0.044715f;
    const float z = k0 * (v + k1 * v * v * v);
    const float t = exp2_f(z * -2.8853900817779268f);   // e^{-2z}
    return v * __builtin_amdgcn_rcpf(1.0f + t);
}

__device__ __forceinline__ void gl_lds16(const short* gsrc, short* lds) {
    __builtin_amdgcn_global_load_lds(
        (const __attribute__((address_space(1))) void*)gsrc,
        (__attribute__((address_space(3))) void*)lds, 16, 0, 0);
}

// ---------------------------------------------------------------------------
// Fused prep: blocks 0..3071 transpose+convert all 4 weights;
// blocks 3072..5119 LayerNorm1 (x -> xn, bf16). Independent streams overlap.
// ---------------------------------------------------------------------------
__global__ __launch_bounds__(256) void prep_fused(
    const float* __restrict__ W0, short* __restrict__ D0,   // 512x1536
    const float* __restrict__ W1, short* __restrict__ D1,   // 512x512
    const float* __restrict__ W2, short* __restrict__ D2,   // 512x2048
    const float* __restrict__ W3, short* __restrict__ D3,   // 2048x512
    const float* __restrict__ x,  const float* __restrict__ lng,
    const float* __restrict__ lnb, short* __restrict__ xout) {
    __shared__ float tile[32][33];
    int bid = blockIdx.x;

    if (bid >= 3072) {
        // ---- LN path: 4 rows per block, one wave per row ----
        const int row = (bid - 3072) * 4 + (threadIdx.x >> 6);
        const int lane = threadIdx.x & 63;
        const float* xr = x + (size_t)row * C_;

        float4 v0 = *(const float4*)(xr + lane * 8);
        float4 v1 = *(const float4*)(xr + lane * 8 + 4);

        float s  = v0.x + v0.y + v0.z + v0.w + v1.x + v1.y + v1.z + v1.w;
        float s2 = v0.x*v0.x + v0.y*v0.y + v0.z*v0.z + v0.w*v0.w
                 + v1.x*v1.x + v1.y*v1.y + v1.z*v1.z + v1.w*v1.w;
        #pragma unroll
        for (int off = 32; off; off >>= 1) {
            s  += __shfl_down(s, off);
            s2 += __shfl_down(s2, off);
        }
        s  = __shfl(s, 0);
        s2 = __shfl(s2, 0);

        const float mu  = s * (1.0f / C_);
        const float var = s2 * (1.0f / C_) - mu * mu;
        const float rs  = rsqrtf(var + EPS_);

        float4 g0 = *(const float4*)(lng + lane * 8);
        float4 g1 = *(const float4*)(lng + lane * 8 + 4);
        float4 b0 = *(const float4*)(lnb + lane * 8);
        float4 b1 = *(const float4*)(lnb + lane * 8 + 4);

        short8v o;
        o[0] = f2bf((v0.x - mu) * rs * g0.x + b0.x);
        o[1] = f2bf((v0.y - mu) * rs * g0.y + b0.y);
        o[2] = f2bf((v0.z - mu) * rs * g0.z + b0.z);
        o[3] = f2bf((v0.w - mu) * rs * g0.w + b0.w);
        o[4] = f2bf((v1.x - mu) * rs * g1.x + b1.x);
        o[5] = f2bf((v1.y - mu) * rs * g1.y + b1.y);
        o[6] = f2bf((v1.z - mu) * rs * g1.z + b1.z);
        o[7] = f2bf((v1.w - mu) * rs * g1.w + b1.w);
        *(short8v*)(xout + (size_t)row * C_ + lane * 8) = o;
        return;
    }

    // ---- weight transpose path ----
    const float* W; short* D; int K, N, nx;
    if (bid < 768)       {             W = W0; D = D0; K = 512;  N = 1536; nx = 48; }
    else if (bid < 1024) { bid -= 768;  W = W1; D = D1; K = 512;  N = 512;  nx = 16; }
    else if (bid < 2048) { bid -= 1024; W = W2; D = D2; K = 512;  N = 2048; nx = 64; }
    else                 { bid -= 2048; W = W3; D = D3; K = 2048; N = 512;  nx = 16; }
    const int n0 = (bid % nx) * 32, k0 = (bid / nx) * 32;
    const int tx = threadIdx.x & 31, ty = threadIdx.x >> 5;   // ty 0..7
    #pragma unroll
    for (int j = 0; j < 4; j++)
        tile[ty + j * 8][tx] = W[(size_t)(k0 + ty + j * 8) * N + n0 + tx];
    __syncthreads();
    #pragma unroll
    for (int j = 0; j < 4; j++)
        D[(size_t)(n0 + ty + j * 8) * K + k0 + tx] = f2bf(tile[tx][ty + j * 8]);
}

// ---------------------------------------------------------------------------
// LayerNorm: 256 threads = 4 waves, one row per wave. fp32 in -> bf16 out.
// ---------------------------------------------------------------------------
__global__ __launch_bounds__(256) void ln_bf16(const float* __restrict__ x,
                                               const float* __restrict__ g,
                                               const float* __restrict__ b,
                                               short* __restrict__ out) {
    const int row = blockIdx.x * 4 + (threadIdx.x >> 6);
    const int lane = threadIdx.x & 63;
    const float* xr = x + (size_t)row * C_;

    float4 v0 = *(const float4*)(xr + lane * 8);
    float4 v1 = *(const float4*)(xr + lane * 8 + 4);

    float s  = v0.x + v0.y + v0.z + v0.w + v1.x + v1.y + v1.z + v1.w;
    float s2 = v0.x*v0.x + v0.y*v0.y + v0.z*v0.z + v0.w*v0.w
             + v1.x*v1.x + v1.y*v1.y + v1.z*v1.z + v1.w*v1.w;
    #pragma unroll
    for (int off = 32; off; off >>= 1) {
        s  += __shfl_down(s, off);
        s2 += __shfl_down(s2, off);
    }
    s  = __shfl(s, 0);
    s2 = __shfl(s2, 0);

    const float mu  = s * (1.0f / C_);
    const float var = s2 * (1.0f / C_) - mu * mu;
    const float rs  = rsqrtf(var + EPS_);

    float4 g0 = *(const float4*)(g + lane * 8);
    float4 g1 = *(const float4*)(g + lane * 8 + 4);
    float4 b0 = *(const float4*)(b + lane * 8);
    float4 b1 = *(const float4*)(b + lane * 8 + 4);

    short8v o;
    o[0] = f2bf((v0.x - mu) * rs * g0.x + b0.x);
    o[1] = f2bf((v0.y - mu) * rs * g0.y + b0.y);
    o[2] = f2bf((v0.z - mu) * rs * g0.z + b0.z);
    o[3] = f2bf((v0.w - mu) * rs * g0.w + b0.w);
    o[4] = f2bf((v1.x - mu) * rs * g1.x + b1.x);
    o[5] = f2bf((v1.y - mu) * rs * g1.y + b1.y);
    o[6] = f2bf((v1.z - mu) * rs * g1.z + b1.z);
    o[7] = f2bf((v1.w - mu) * rs * g1.w + b1.w);
    *(short8v*)(out + (size_t)row * C_ + lane * 8) = o;
}

// ---------------------------------------------------------------------------
// bf16 MFMA GEMM, 64x128x128 tile, SINGLE-buffered (48 KB LDS, 3 blocks/CU).
// r17/r20-proven local optimum. 256B LDS rows, chunk-XOR swizzle.
// VFUSE=1 (qkv GEMM): n0>=1024 tiles write acc directly into Vt with the
// kv-permutation t' = (t&~31)|(8g+4*mt+rr)  (BM=64: t%32 = 16*mt+4g+rr).
// Epilogue bf16 converts use f2bf_h (pairs fuse to v_cvt_pk_bf16_f32).
// ---------------------------------------------------------------------------
template<int ACT, int OUTBF16, int HASRES, int VFUSE>
__global__ __launch_bounds__(256) void gemm_bf16(const short* __restrict__ A,
                                                 const short* __restrict__ Wt,
                                                 const float* __restrict__ bias,
                                                 const float* __restrict__ res,
                                                 void* __restrict__ outp,
                                                 int M, int N, int K,
                                                 int GX, int CY,
                                                 short* __restrict__ vtb) {
    __shared__ short As[64 * 128];       // 16 KB
    __shared__ short Bs[128 * 128];      // 32 KB

    const int bid = blockIdx.x;
    const int xcd = bid & 7, jb = bid >> 3;
    const int by = xcd * CY + jb / GX;
    const int bx = jb % GX;

    const int t = threadIdx.x;
    const int w = t >> 6;
    const int l = t & 63;
    const int c = l & 15;
    const int g = l >> 4;
    const int wr = w >> 1, wc = w & 1;
    const int m0 = by * 64, n0 = bx * 128;

    const int r16 = t >> 4;
    const int sch = ((t & 15) ^ (r16 & 7)) * 8;       // shorts
    const short* Asrc = A  + (size_t)(m0 + r16) * K + sch;
    const short* Bsrc = Wt + (size_t)(n0 + r16) * K + sch;

    auto stage = [&](int kt) {
        #pragma unroll
        for (int i = 0; i < 4; i++)
            gl_lds16(Asrc + (size_t)(16 * i) * K + kt, &As[i * 2048 + w * 512]);
        #pragma unroll
        for (int i = 0; i < 8; i++)
            gl_lds16(Bsrc + (size_t)(16 * i) * K + kt, &Bs[i * 2048 + w * 512]);
    };

    f32x4 acc[2][4] = {};

    for (int kt = 0; kt < K; kt += 128) {
        stage(kt);
        __syncthreads();     // drains vmcnt (gl_lds) for all waves

        #pragma unroll
        for (int j = 0; j < 4; j++) {     // k-steps of 32 within the 128
            const int ckj = ((4 * j + g) ^ (c & 7)) * 8;   // shorts
            bf16x8 af[2], bfr[4];
            #pragma unroll
            for (int mt = 0; mt < 2; mt++)
                af[mt] = *(const bf16x8*)&As[(wr * 32 + mt * 16 + c) * 128 + ckj];
            #pragma unroll
            for (int nt = 0; nt < 4; nt++)
                bfr[nt] = *(const bf16x8*)&Bs[(wc * 64 + nt * 16 + c) * 128 + ckj];
            #pragma unroll
            for (int mt = 0; mt < 2; mt++)
                #pragma unroll
                for (int nt = 0; nt < 4; nt++)
                    acc[mt][nt] = __builtin_amdgcn_mfma_f32_16x16x32_bf16(
                        af[mt], bfr[nt], acc[mt][nt], 0, 0, 0);
        }

        __syncthreads();     // all reads done before next stage overwrites
    }

    const int colb = n0 + wc * 64;
    float bias_v[4];
    #pragma unroll
    for (int nt = 0; nt < 4; nt++) bias_v[nt] = bias[colb + nt * 16 + c];

    if (VFUSE && n0 >= 1024) {
        // V-fused epilogue: Vt[(b*8+h)*64+d][t'] = bf16(acc + bias)
        const int bq   = m0 >> 12;                 // batch index
        const int trow = (m0 & 4095) + wr * 32;    // t base (&~31 part)
        #pragma unroll
        for (int mt = 0; mt < 2; mt++) {
            const int tb = trow + 8 * g + 4 * mt;
            #pragma unroll
            for (int nt = 0; nt < 4; nt++) {
                const int vcol = colb + nt * 16 + c - 1024;
                const int hh = vcol >> 6, dd = vcol & 63;
                short4v pk;
                #pragma unroll
                for (int rr = 0; rr < 4; rr++)
                    pk[rr] = f2bf_h(acc[mt][nt][rr] + bias_v[nt]);
                *(short4v*)&vtb[((size_t)((bq * 8 + hh) * 64 + dd)) * T_ + tb] = pk;
            }
        }
        return;
    }

    float* out_f = (float*)outp;
    short* out_h = (short*)outp;

    #pragma unroll
    for (int mt = 0; mt < 2; mt++) {
        #pragma unroll
        for (int rr = 0; rr < 4; rr++) {
            const size_t row = (size_t)(m0 + wr * 32 + mt * 16 + 4 * g + rr);
            #pragma unroll
            for (int nt = 0; nt < 4; nt++) {
                const int col = colb + nt * 16 + c;
                float v = acc[mt][nt][rr] + bias_v[nt];
                if (ACT) v = gelu_f(v);
                if (HASRES) v += res[row * N + col];
                if (OUTBF16) out_h[row * N + col] = f2bf_h(v);
                else         out_f[row * N + col] = v;
            }
        }
    }
}

// ---------------------------------------------------------------------------
// Flash attention, bf16 MFMA. 512 blocks x 512 threads (8 waves).
// Q-supertile = 128 rows; K/V staged once per supertile; causal via
// wave-uniform diag tile dw = 2Qt + (w>>2). Balance Qt = lo ? 31-qtr : qtr.
// XCD-bijective (b,h) map; fixed-shift softmax; l via ones-MFMA; ping-pong.
// (r21-measured 56.6 us — attn floor for this structure.)
// ---------------------------------------------------------------------------
__global__ __launch_bounds__(512) void attn_mfma(const short* __restrict__ qkv,
                                                 const short* __restrict__ Vt,
                                                 short* __restrict__ y) {
    __shared__ union {
        struct { short K[2][64 * 64]; short V[2][64 * 64]; } s;   // 32 KB
        float O[8][16][68];                                       // 34.8 KB
    } sm;

    // bid = xcd + 8*(lo*32 + qtr)
    const int bid = blockIdx.x;
    const int xcd = bid & 7, jj = bid >> 3;
    const int lo = jj >> 5;
    const int qtr = jj & 31;
    const int Qt = lo ? (31 - qtr) : qtr;      // per-CU pair {Qt, 31-Qt}
    const int g16 = xcd * 2 + lo;
    const int b = g16 >> 3, h = g16 & 7;

    const int tid = threadIdx.x, w = tid >> 6, lid = tid & 63;
    const int c = lid & 15, g = lid >> 4;
    const size_t base = (size_t)b * T_;
    const int bh = g16;

    const float qmul = 0.04419417382415922f * 1.4426950408889634f; // 1/sqrt(512)*log2e

    // Q fragment (B operand), pre-scaled; wave w covers q rows Qt*128+w*16+c
    bf16x8 qf0, qf1;
    {
        const short* qa = qkv + (base + Qt * 128 + w * 16 + c) * 1536 + h * 64 + g * 8;
        bf16x8 a0 = *(const bf16x8*)qa;
        bf16x8 a1 = *(const bf16x8*)(qa + 32);
        #pragma unroll
        for (int i = 0; i < 8; i++) {
            qf0[i] = f2bf_h(bf2f(a0[i]) * qmul);
            qf1[i] = f2bf_h(bf2f(a1[i]) * qmul);
        }
    }

    const f32x4 kZero = {0.f, 0.f, 0.f, 0.f};
    bf16x8 kOnes;
    #pragma unroll
    for (int i = 0; i < 8; i++) kOnes[i] = (short)0x3F80;   // bf16 1.0

    f32x4 ot[4] = {};
    f32x4 lacc = {0.f, 0.f, 0.f, 0.f};   // l via ones-MFMA
    const int qg = Qt * 128 + w * 16 + c;
    const int dw = 2 * Qt + (w >> 2);    // this wave's diagonal kv-tile
    const int NT = 2 * Qt + 2;           // kv-tiles to stage (even)

    // staging: 512 threads x 16B cover the full 64x64 K (and V) tile.
    const int sr = tid >> 3;                         // 0..63
    const int sc = ((tid & 7) ^ (sr & 7)) * 8;       // swizzled source chunk

    auto stage = [&](short* Kb, short* Vb, int st) {
        const short* ks = qkv + (base + st * 64 + sr) * 1536 + 512 + h * 64 + sc;
        const short* vs = Vt + ((size_t)(bh * 64 + sr)) * T_ + st * 64 + sc;
        gl_lds16(ks, Kb + w * 512);
        gl_lds16(vs, Vb + w * 512);
    };

    const int rx = c & 7;
    const int ck0 = g ^ rx;              // LDS chunk for source chunk g
    const int ck1 = ck0 ^ 4;             // LDS chunk for source chunk 4+g

    // full tile: QK^T -> exp2 -> l(ones-MFMA) -> PV
    auto tile = [&](const short* Kb, const short* Vb, bool mask_diag) {
        f32x4 s[4];
        __builtin_amdgcn_s_setprio(1);
        #pragma unroll
        for (int mt = 0; mt < 4; mt++) {
            const short* krow = Kb + (mt * 16 + c) * 64;
            bf16x8 k0 = *(const bf16x8*)&krow[ck0 * 8];
            bf16x8 k1 = *(const bf16x8*)&krow[ck1 * 8];
            f32x4 z = __builtin_amdgcn_mfma_f32_16x16x32_bf16(k0, qf0, kZero, 0, 0, 0);
            s[mt] = __builtin_amdgcn_mfma_f32_16x16x32_bf16(k1, qf1, z, 0, 0, 0);
        }
        __builtin_amdgcn_s_setprio(0);

        float p[4][4];
        #pragma unroll
        for (int mt = 0; mt < 4; mt++)
            #pragma unroll
            for (int rr = 0; rr < 4; rr++) {
                float v = s[mt][rr];
                if (mask_diag && (dw * 64 + mt * 16 + 4 * g + rr > qg)) v = -1e30f;
                p[mt][rr] = exp2_f(v);          // exp2(-1e30) -> 0
            }

        bf16x8 pb0, pb1;
        #pragma unroll
        for (int i = 0; i < 8; i++) {
            pb0[i] = f2bf_h(p[(i >> 2)][i & 3]);
            pb1[i] = f2bf_h(p[2 + (i >> 2)][i & 3]);
        }
        __builtin_amdgcn_s_setprio(1);
        // l contribution on the matrix pipe: out[r][c] = sum_k p[k][c]
        lacc = __builtin_amdgcn_mfma_f32_16x16x32_bf16(kOnes, pb0, lacc, 0, 0, 0);
        lacc = __builtin_amdgcn_mfma_f32_16x16x32_bf16(kOnes, pb1, lacc, 0, 0, 0);
        #pragma unroll
        for (int dt = 0; dt < 4; dt++) {
            const short* vrow = Vb + (16 * dt + c) * 64;
            bf16x8 va0 = *(const bf16x8*)&vrow[ck0 * 8];
            bf16x8 va1 = *(const bf16x8*)&vrow[ck1 * 8];
            ot[dt] = __builtin_amdgcn_mfma_f32_16x16x32_bf16(va0, pb0, ot[dt], 0, 0, 0);
            ot[dt] = __builtin_amdgcn_mfma_f32_16x16x32_bf16(va1, pb1, ot[dt], 0, 0, 0);
        }
        __builtin_amdgcn_s_setprio(0);
    };

    short* K0 = sm.s.K[0]; short* K1 = sm.s.K[1];
    short* V0 = sm.s.V[0]; short* V1 = sm.s.V[1];

    stage(K0, V0, 0);
    asm volatile("s_waitcnt vmcnt(0)" ::: "memory");
    __syncthreads();

    // NT is even: clean pairs. Waves with dw < st skip compute (uniform branch)
    int st = 0;
    while (st + 2 <= NT) {
        if (st + 1 < NT) stage(K1, V1, st + 1);
        if (st <= dw) tile(K0, V0, st == dw);
        asm volatile("s_waitcnt vmcnt(0)" ::: "memory");
        __syncthreads();
        if (st + 2 < NT) stage(K0, V0, st + 2);
        if (st + 1 <= dw) tile(K1, V1, st + 1 == dw);
        asm volatile("s_waitcnt vmcnt(0)" ::: "memory");
        __syncthreads();
        st += 2;
    }

    // epilogue: O^T/l -> LDS transpose.  l = lacc[0] (all regs identical)
    const float inv = 1.0f / lacc[0];
    #pragma unroll
    for (int dt = 0; dt < 4; dt++)
        #pragma unroll
        for (int rr = 0; rr < 4; rr++)
            sm.O[w][c][16 * dt + 4 * g + rr] = ot[dt][rr] * inv;
    // wave-local write->read (per-wave LDS ordering + compiler lgkmcnt)
    const int q = lid >> 2, ch = lid & 3;
    short* dst = y + (base + Qt * 128 + w * 16 + q) * 512 + h * 64 + ch * 16;
    short8v o0, o1;
    #pragma unroll
    for (int j = 0; j < 8; j++) o0[j] = f2bf(sm.O[w][q][ch * 16 + j]);
    #pragma unroll
    for (int j = 0; j < 8; j++) o1[j] = f2bf(sm.O[w][q][ch * 16 + 8 + j]);
    *(short8v*)dst = o0;
    *(short8v*)(dst + 8) = o1;
}

// ---------------------------------------------------------------------------
// Orchestration
// ---------------------------------------------------------------------------
extern "C" void kernel_launch(void* const* d_in, const int* in_sizes, int n_in,
                              void* d_out, int out_size, void* d_ws, size_t ws_size,
                              hipStream_t stream) {
    const float* x           = (const float*)d_in[0];
    const float* w_qkv       = (const float*)d_in[1];
    const float* b_qkv       = (const float*)d_in[2];
    const float* w_attn_proj = (const float*)d_in[3];
    const float* b_attn_proj = (const float*)d_in[4];
    const float* w_fc        = (const float*)d_in[5];
    const float* b_fc        = (const float*)d_in[6];
    const float* w_mlp_proj  = (const float*)d_in[7];
    const float* b_mlp_proj  = (const float*)d_in[8];
    const float* ln1_g       = (const float*)d_in[9];
    const float* ln1_b       = (const float*)d_in[10];
    const float* ln2_g       = (const float*)d_in[11];
    const float* ln2_b       = (const float*)d_in[12];

    float* out = (float*)d_out;
    short* ws16 = (short*)d_ws;

    // ws layout (bf16 elems), ~65 MB total
    short* wqkvT = ws16;                                   // [1536][512]
    short* waT   = wqkvT + 1536 * 512;                     // [512][512]
    short* wfcT  = waT   + 512 * 512;                      // [2048][512]
    short* wmT   = wfcT  + 2048 * 512;                     // [512][2048]
    short* xn    = wmT   + 512 * 2048;                     // [8192][512]
    short* ybuf  = xn    + (size_t)BT_ * 512;              // [8192][512]
    short* qkvh  = ybuf  + (size_t)BT_ * 512;              // [8192][2048] (q|k|unused, h)
    short* vtb   = qkvh  + (size_t)BT_ * 2048;             // [2][8][64][4096]

    // 0+1) weights -> bf16 transposed AND xn1 = LN(x), one fused launch
    prep_fused<<<3072 + BT_ / 4, 256, 0, stream>>>(
        w_qkv, wqkvT, w_attn_proj, waT, w_fc, wfcT, w_mlp_proj, wmT,
        x, ln1_g, ln1_b, xn);

    // 2) qkv = xn1 @ w_qkv + b_qkv  (bf16 out; V-region fused into Vt)
    gemm_bf16<0, 1, 0, 1><<<12 * 128, 256, 0, stream>>>(
        xn, wqkvT, b_qkv, nullptr, qkvh, BT_, 1536, 512, 12, 16, vtb);

    // 3) y = attention(qkv, Vt)  (bf16 out) — 512 blocks x 8 waves
    attn_mfma<<<512, 512, 0, stream>>>(qkvh, vtb, ybuf);

    // 4) x2 = x + y @ w_attn_proj + b  (f32 out -> d_out)  GX=4 CY=16
    gemm_bf16<0, 0, 1, 0><<<4 * 128, 256, 0, stream>>>(
        ybuf, waT, b_attn_proj, x, out, BT_, 512, 512, 4, 16, nullptr);

    // 5) xn2 = LN(x2)
    ln_bf16<<<BT_ / 4, 256, 0, stream>>>(out, ln2_g, ln2_b, xn);

    // 6) h = gelu(xn2 @ w_fc + b)  (bf16 out)  GX=16 CY=16
    gemm_bf16<1, 1, 0, 0><<<16 * 128, 256, 0, stream>>>(
        xn, wfcT, b_fc, nullptr, qkvh, BT_, 2048, 512, 16, 16, nullptr);

    // 7) out = x2 + h @ w_mlp_proj + b  (f32 out -> d_out)  GX=4 CY=16
    gemm_bf16<0, 0, 1, 0><<<4 * 128, 256, 0, stream>>>(
        qkvh, wmT, b_mlp_proj, out, out, BT_, 512, 2048, 4, 16, nullptr);
}

// Round 24
// 158.460 us; speedup vs baseline: 1.1969x; 1.0000x over previous
//
#include <hip/hip_runtime.h>
#include <hip/hip_bf16.h>
#include <math.h>

constexpr int B_ = 2;
constexpr int T_ = 4096;
constexpr int C_ = 512;
constexpr int H_ = 8;
constexpr int BT_ = B_ * T_;          // 8192 rows
constexpr float EPS_ = 1e-5f;

typedef __attribute__((ext_vector_type(8))) short bf16x8;   // 8 bf16 (4 VGPRs)
typedef __attribute__((ext_vector_type(4))) short short4v;
typedef __attribute__((ext_vector_type(8))) short short8v;
typedef __attribute__((ext_vector_type(4))) float f32x4;

__device__ __forceinline__ float bf2f(short s) {
    return __uint_as_float(((unsigned)(unsigned short)s) << 16);
}
// RTNE f32->bf16; adjacent pairs fuse into v_cvt_pk_bf16_f32 (m240)
__device__ __forceinline__ short f2bf_h(float f) {
    union { __hip_bfloat16 h; short s; } u;
    u.h = __float2bfloat16(f);
    return u.s;
}
// raw 2^x (1 inst; hw handles large-negative -> 0)
__device__ __forceinline__ float exp2_f(float x) {
    float r;
    asm("v_exp_f32 %0, %1" : "=v"(r) : "v"(x));
    return r;
}

// tanh-GELU via identity 0.5v(1+tanh(z)) = v/(1+e^{-2z}); ~7 VALU ops.
__device__ __forceinline__ float gelu_f(float v) {
    const float k0 = 0.7978845608028654f;   // sqrt(2/pi)
    const float k1 = 0.044715f;
    const float z = k0 * (v + k1 * v * v * v);
    const float t = exp2_f(z * -2.8853900817779268f);   // e^{-2z}
    return v * __builtin_amdgcn_rcpf(1.0f + t);
}

__device__ __forceinline__ void gl_lds16(const short* gsrc, short* lds) {
    __builtin_amdgcn_global_load_lds(
        (const __attribute__((address_space(1))) void*)gsrc,
        (__attribute__((address_space(3))) void*)lds, 16, 0, 0);
}

// ---------------------------------------------------------------------------
// Fused prep: blocks 0..3071 transpose+convert all 4 weights;
// blocks 3072..5119 LayerNorm1 (x -> xn, bf16). Independent streams overlap.
// ---------------------------------------------------------------------------
__global__ __launch_bounds__(256) void prep_fused(
    const float* __restrict__ W0, short* __restrict__ D0,   // 512x1536
    const float* __restrict__ W1, short* __restrict__ D1,   // 512x512
    const float* __restrict__ W2, short* __restrict__ D2,   // 512x2048
    const float* __restrict__ W3, short* __restrict__ D3,   // 2048x512
    const float* __restrict__ x,  const float* __restrict__ lng,
    const float* __restrict__ lnb, short* __restrict__ xout) {
    __shared__ float tile[32][33];
    int bid = blockIdx.x;

    if (bid >= 3072) {
        // ---- LN path: 4 rows per block, one wave per row ----
        const int row = (bid - 3072) * 4 + (threadIdx.x >> 6);
        const int lane = threadIdx.x & 63;
        const float* xr = x + (size_t)row * C_;

        float4 v0 = *(const float4*)(xr + lane * 8);
        float4 v1 = *(const float4*)(xr + lane * 8 + 4);

        float s  = v0.x + v0.y + v0.z + v0.w + v1.x + v1.y + v1.z + v1.w;
        float s2 = v0.x*v0.x + v0.y*v0.y + v0.z*v0.z + v0.w*v0.w
                 + v1.x*v1.x + v1.y*v1.y + v1.z*v1.z + v1.w*v1.w;
        #pragma unroll
        for (int off = 32; off; off >>= 1) {
            s  += __shfl_down(s, off);
            s2 += __shfl_down(s2, off);
        }
        s  = __shfl(s, 0);
        s2 = __shfl(s2, 0);

        const float mu  = s * (1.0f / C_);
        const float var = s2 * (1.0f / C_) - mu * mu;
        const float rs  = rsqrtf(var + EPS_);

        float4 g0 = *(const float4*)(lng + lane * 8);
        float4 g1 = *(const float4*)(lng + lane * 8 + 4);
        float4 b0 = *(const float4*)(lnb + lane * 8);
        float4 b1 = *(const float4*)(lnb + lane * 8 + 4);

        short8v o;
        o[0] = f2bf_h((v0.x - mu) * rs * g0.x + b0.x);
        o[1] = f2bf_h((v0.y - mu) * rs * g0.y + b0.y);
        o[2] = f2bf_h((v0.z - mu) * rs * g0.z + b0.z);
        o[3] = f2bf_h((v0.w - mu) * rs * g0.w + b0.w);
        o[4] = f2bf_h((v1.x - mu) * rs * g1.x + b1.x);
        o[5] = f2bf_h((v1.y - mu) * rs * g1.y + b1.y);
        o[6] = f2bf_h((v1.z - mu) * rs * g1.z + b1.z);
        o[7] = f2bf_h((v1.w - mu) * rs * g1.w + b1.w);
        *(short8v*)(xout + (size_t)row * C_ + lane * 8) = o;
        return;
    }

    // ---- weight transpose path ----
    const float* W; short* D; int K, N, nx;
    if (bid < 768)       {             W = W0; D = D0; K = 512;  N = 1536; nx = 48; }
    else if (bid < 1024) { bid -= 768;  W = W1; D = D1; K = 512;  N = 512;  nx = 16; }
    else if (bid < 2048) { bid -= 1024; W = W2; D = D2; K = 512;  N = 2048; nx = 64; }
    else                 { bid -= 2048; W = W3; D = D3; K = 2048; N = 512;  nx = 16; }
    const int n0 = (bid % nx) * 32, k0 = (bid / nx) * 32;
    const int tx = threadIdx.x & 31, ty = threadIdx.x >> 5;   // ty 0..7
    #pragma unroll
    for (int j = 0; j < 4; j++)
        tile[ty + j * 8][tx] = W[(size_t)(k0 + ty + j * 8) * N + n0 + tx];
    __syncthreads();
    #pragma unroll
    for (int j = 0; j < 4; j++)
        D[(size_t)(n0 + ty + j * 8) * K + k0 + tx] = f2bf_h(tile[tx][ty + j * 8]);
}

// ---------------------------------------------------------------------------
// LayerNorm: 256 threads = 4 waves, one row per wave. fp32 in -> bf16 out.
// ---------------------------------------------------------------------------
__global__ __launch_bounds__(256) void ln_bf16(const float* __restrict__ x,
                                               const float* __restrict__ g,
                                               const float* __restrict__ b,
                                               short* __restrict__ out) {
    const int row = blockIdx.x * 4 + (threadIdx.x >> 6);
    const int lane = threadIdx.x & 63;
    const float* xr = x + (size_t)row * C_;

    float4 v0 = *(const float4*)(xr + lane * 8);
    float4 v1 = *(const float4*)(xr + lane * 8 + 4);

    float s  = v0.x + v0.y + v0.z + v0.w + v1.x + v1.y + v1.z + v1.w;
    float s2 = v0.x*v0.x + v0.y*v0.y + v0.z*v0.z + v0.w*v0.w
             + v1.x*v1.x + v1.y*v1.y + v1.z*v1.z + v1.w*v1.w;
    #pragma unroll
    for (int off = 32; off; off >>= 1) {
        s  += __shfl_down(s, off);
        s2 += __shfl_down(s2, off);
    }
    s  = __shfl(s, 0);
    s2 = __shfl(s2, 0);

    const float mu  = s * (1.0f / C_);
    const float var = s2 * (1.0f / C_) - mu * mu;
    const float rs  = rsqrtf(var + EPS_);

    float4 g0 = *(const float4*)(g + lane * 8);
    float4 g1 = *(const float4*)(g + lane * 8 + 4);
    float4 b0 = *(const float4*)(b + lane * 8);
    float4 b1 = *(const float4*)(b + lane * 8 + 4);

    short8v o;
    o[0] = f2bf_h((v0.x - mu) * rs * g0.x + b0.x);
    o[1] = f2bf_h((v0.y - mu) * rs * g0.y + b0.y);
    o[2] = f2bf_h((v0.z - mu) * rs * g0.z + b0.z);
    o[3] = f2bf_h((v0.w - mu) * rs * g0.w + b0.w);
    o[4] = f2bf_h((v1.x - mu) * rs * g1.x + b1.x);
    o[5] = f2bf_h((v1.y - mu) * rs * g1.y + b1.y);
    o[6] = f2bf_h((v1.z - mu) * rs * g1.z + b1.z);
    o[7] = f2bf_h((v1.w - mu) * rs * g1.w + b1.w);
    *(short8v*)(out + (size_t)row * C_ + lane * 8) = o;
}

// ---------------------------------------------------------------------------
// bf16 MFMA GEMM, 64x128x128 tile, SINGLE-buffered (48 KB LDS, 3 blocks/CU).
// r17/r20-proven local optimum. 256B LDS rows, chunk-XOR swizzle.
// VFUSE=1 (qkv GEMM): n0>=1024 tiles write acc directly into Vt with the
// kv-permutation t' = (t&~31)|(8g+4*mt+rr)  (BM=64: t%32 = 16*mt+4g+rr).
// Epilogue bf16 converts use f2bf_h (pairs fuse to v_cvt_pk_bf16_f32).
// ---------------------------------------------------------------------------
template<int ACT, int OUTBF16, int HASRES, int VFUSE>
__global__ __launch_bounds__(256) void gemm_bf16(const short* __restrict__ A,
                                                 const short* __restrict__ Wt,
                                                 const float* __restrict__ bias,
                                                 const float* __restrict__ res,
                                                 void* __restrict__ outp,
                                                 int M, int N, int K,
                                                 int GX, int CY,
                                                 short* __restrict__ vtb) {
    __shared__ short As[64 * 128];       // 16 KB
    __shared__ short Bs[128 * 128];      // 32 KB

    const int bid = blockIdx.x;
    const int xcd = bid & 7, jb = bid >> 3;
    const int by = xcd * CY + jb / GX;
    const int bx = jb % GX;

    const int t = threadIdx.x;
    const int w = t >> 6;
    const int l = t & 63;
    const int c = l & 15;
    const int g = l >> 4;
    const int wr = w >> 1, wc = w & 1;
    const int m0 = by * 64, n0 = bx * 128;

    const int r16 = t >> 4;
    const int sch = ((t & 15) ^ (r16 & 7)) * 8;       // shorts
    const short* Asrc = A  + (size_t)(m0 + r16) * K + sch;
    const short* Bsrc = Wt + (size_t)(n0 + r16) * K + sch;

    auto stage = [&](int kt) {
        #pragma unroll
        for (int i = 0; i < 4; i++)
            gl_lds16(Asrc + (size_t)(16 * i) * K + kt, &As[i * 2048 + w * 512]);
        #pragma unroll
        for (int i = 0; i < 8; i++)
            gl_lds16(Bsrc + (size_t)(16 * i) * K + kt, &Bs[i * 2048 + w * 512]);
    };

    f32x4 acc[2][4] = {};

    for (int kt = 0; kt < K; kt += 128) {
        stage(kt);
        __syncthreads();     // drains vmcnt (gl_lds) for all waves

        #pragma unroll
        for (int j = 0; j < 4; j++) {     // k-steps of 32 within the 128
            const int ckj = ((4 * j + g) ^ (c & 7)) * 8;   // shorts
            bf16x8 af[2], bfr[4];
            #pragma unroll
            for (int mt = 0; mt < 2; mt++)
                af[mt] = *(const bf16x8*)&As[(wr * 32 + mt * 16 + c) * 128 + ckj];
            #pragma unroll
            for (int nt = 0; nt < 4; nt++)
                bfr[nt] = *(const bf16x8*)&Bs[(wc * 64 + nt * 16 + c) * 128 + ckj];
            #pragma unroll
            for (int mt = 0; mt < 2; mt++)
                #pragma unroll
                for (int nt = 0; nt < 4; nt++)
                    acc[mt][nt] = __builtin_amdgcn_mfma_f32_16x16x32_bf16(
                        af[mt], bfr[nt], acc[mt][nt], 0, 0, 0);
        }

        __syncthreads();     // all reads done before next stage overwrites
    }

    const int colb = n0 + wc * 64;
    float bias_v[4];
    #pragma unroll
    for (int nt = 0; nt < 4; nt++) bias_v[nt] = bias[colb + nt * 16 + c];

    if (VFUSE && n0 >= 1024) {
        // V-fused epilogue: Vt[(b*8+h)*64+d][t'] = bf16(acc + bias)
        const int bq   = m0 >> 12;                 // batch index
        const int trow = (m0 & 4095) + wr * 32;    // t base (&~31 part)
        #pragma unroll
        for (int mt = 0; mt < 2; mt++) {
            const int tb = trow + 8 * g + 4 * mt;
            #pragma unroll
            for (int nt = 0; nt < 4; nt++) {
                const int vcol = colb + nt * 16 + c - 1024;
                const int hh = vcol >> 6, dd = vcol & 63;
                short4v pk;
                #pragma unroll
                for (int rr = 0; rr < 4; rr++)
                    pk[rr] = f2bf_h(acc[mt][nt][rr] + bias_v[nt]);
                *(short4v*)&vtb[((size_t)((bq * 8 + hh) * 64 + dd)) * T_ + tb] = pk;
            }
        }
        return;
    }

    float* out_f = (float*)outp;
    short* out_h = (short*)outp;

    #pragma unroll
    for (int mt = 0; mt < 2; mt++) {
        #pragma unroll
        for (int rr = 0; rr < 4; rr++) {
            const size_t row = (size_t)(m0 + wr * 32 + mt * 16 + 4 * g + rr);
            #pragma unroll
            for (int nt = 0; nt < 4; nt++) {
                const int col = colb + nt * 16 + c;
                float v = acc[mt][nt][rr] + bias_v[nt];
                if (ACT) v = gelu_f(v);
                if (HASRES) v += res[row * N + col];
                if (OUTBF16) out_h[row * N + col] = f2bf_h(v);
                else         out_f[row * N + col] = v;
            }
        }
    }
}

// ---------------------------------------------------------------------------
// Flash attention, bf16 MFMA. 512 blocks x 512 threads (8 waves).
// Q-supertile = 128 rows; K/V staged once per supertile; causal via
// wave-uniform diag tile dw = 2Qt + (w>>2). Balance Qt = lo ? 31-qtr : qtr.
// XCD-bijective (b,h) map; fixed-shift softmax; l via ones-MFMA; ping-pong.
// (r21-measured 56.6 us — attn floor for this structure.)
// ---------------------------------------------------------------------------
__global__ __launch_bounds__(512) void attn_mfma(const short* __restrict__ qkv,
                                                 const short* __restrict__ Vt,
                                                 short* __restrict__ y) {
    __shared__ union {
        struct { short K[2][64 * 64]; short V[2][64 * 64]; } s;   // 32 KB
        float O[8][16][68];                                       // 34.8 KB
    } sm;

    // bid = xcd + 8*(lo*32 + qtr)
    const int bid = blockIdx.x;
    const int xcd = bid & 7, jj = bid >> 3;
    const int lo = jj >> 5;
    const int qtr = jj & 31;
    const int Qt = lo ? (31 - qtr) : qtr;      // per-CU pair {Qt, 31-Qt}
    const int g16 = xcd * 2 + lo;
    const int b = g16 >> 3, h = g16 & 7;

    const int tid = threadIdx.x, w = tid >> 6, lid = tid & 63;
    const int c = lid & 15, g = lid >> 4;
    const size_t base = (size_t)b * T_;
    const int bh = g16;

    const float qmul = 0.04419417382415922f * 1.4426950408889634f; // 1/sqrt(512)*log2e

    // Q fragment (B operand), pre-scaled; wave w covers q rows Qt*128+w*16+c
    bf16x8 qf0, qf1;
    {
        const short* qa = qkv + (base + Qt * 128 + w * 16 + c) * 1536 + h * 64 + g * 8;
        bf16x8 a0 = *(const bf16x8*)qa;
        bf16x8 a1 = *(const bf16x8*)(qa + 32);
        #pragma unroll
        for (int i = 0; i < 8; i++) {
            qf0[i] = f2bf_h(bf2f(a0[i]) * qmul);
            qf1[i] = f2bf_h(bf2f(a1[i]) * qmul);
        }
    }

    const f32x4 kZero = {0.f, 0.f, 0.f, 0.f};
    bf16x8 kOnes;
    #pragma unroll
    for (int i = 0; i < 8; i++) kOnes[i] = (short)0x3F80;   // bf16 1.0

    f32x4 ot[4] = {};
    f32x4 lacc = {0.f, 0.f, 0.f, 0.f};   // l via ones-MFMA
    const int qg = Qt * 128 + w * 16 + c;
    const int dw = 2 * Qt + (w >> 2);    // this wave's diagonal kv-tile
    const int NT = 2 * Qt + 2;           // kv-tiles to stage (even)

    // staging: 512 threads x 16B cover the full 64x64 K (and V) tile.
    const int sr = tid >> 3;                         // 0..63
    const int sc = ((tid & 7) ^ (sr & 7)) * 8;       // swizzled source chunk

    auto stage = [&](short* Kb, short* Vb, int st) {
        const short* ks = qkv + (base + st * 64 + sr) * 1536 + 512 + h * 64 + sc;
        const short* vs = Vt + ((size_t)(bh * 64 + sr)) * T_ + st * 64 + sc;
        gl_lds16(ks, Kb + w * 512);
        gl_lds16(vs, Vb + w * 512);
    };

    const int rx = c & 7;
    const int ck0 = g ^ rx;              // LDS chunk for source chunk g
    const int ck1 = ck0 ^ 4;             // LDS chunk for source chunk 4+g

    // full tile: QK^T -> exp2 -> l(ones-MFMA) -> PV
    auto tile = [&](const short* Kb, const short* Vb, bool mask_diag) {
        f32x4 s[4];
        __builtin_amdgcn_s_setprio(1);
        #pragma unroll
        for (int mt = 0; mt < 4; mt++) {
            const short* krow = Kb + (mt * 16 + c) * 64;
            bf16x8 k0 = *(const bf16x8*)&krow[ck0 * 8];
            bf16x8 k1 = *(const bf16x8*)&krow[ck1 * 8];
            f32x4 z = __builtin_amdgcn_mfma_f32_16x16x32_bf16(k0, qf0, kZero, 0, 0, 0);
            s[mt] = __builtin_amdgcn_mfma_f32_16x16x32_bf16(k1, qf1, z, 0, 0, 0);
        }
        __builtin_amdgcn_s_setprio(0);

        float p[4][4];
        #pragma unroll
        for (int mt = 0; mt < 4; mt++)
            #pragma unroll
            for (int rr = 0; rr < 4; rr++) {
                float v = s[mt][rr];
                if (mask_diag && (dw * 64 + mt * 16 + 4 * g + rr > qg)) v = -1e30f;
                p[mt][rr] = exp2_f(v);          // exp2(-1e30) -> 0
            }

        bf16x8 pb0, pb1;
        #pragma unroll
        for (int i = 0; i < 8; i++) {
            pb0[i] = f2bf_h(p[(i >> 2)][i & 3]);
            pb1[i] = f2bf_h(p[2 + (i >> 2)][i & 3]);
        }
        __builtin_amdgcn_s_setprio(1);
        // l contribution on the matrix pipe: out[r][c] = sum_k p[k][c]
        lacc = __builtin_amdgcn_mfma_f32_16x16x32_bf16(kOnes, pb0, lacc, 0, 0, 0);
        lacc = __builtin_amdgcn_mfma_f32_16x16x32_bf16(kOnes, pb1, lacc, 0, 0, 0);
        #pragma unroll
        for (int dt = 0; dt < 4; dt++) {
            const short* vrow = Vb + (16 * dt + c) * 64;
            bf16x8 va0 = *(const bf16x8*)&vrow[ck0 * 8];
            bf16x8 va1 = *(const bf16x8*)&vrow[ck1 * 8];
            ot[dt] = __builtin_amdgcn_mfma_f32_16x16x32_bf16(va0, pb0, ot[dt], 0, 0, 0);
            ot[dt] = __builtin_amdgcn_mfma_f32_16x16x32_bf16(va1, pb1, ot[dt], 0, 0, 0);
        }
        __builtin_amdgcn_s_setprio(0);
    };

    short* K0 = sm.s.K[0]; short* K1 = sm.s.K[1];
    short* V0 = sm.s.V[0]; short* V1 = sm.s.V[1];

    stage(K0, V0, 0);
    asm volatile("s_waitcnt vmcnt(0)" ::: "memory");
    __syncthreads();

    // NT is even: clean pairs. Waves with dw < st skip compute (uniform branch)
    int st = 0;
    while (st + 2 <= NT) {
        if (st + 1 < NT) stage(K1, V1, st + 1);
        if (st <= dw) tile(K0, V0, st == dw);
        asm volatile("s_waitcnt vmcnt(0)" ::: "memory");
        __syncthreads();
        if (st + 2 < NT) stage(K0, V0, st + 2);
        if (st + 1 <= dw) tile(K1, V1, st + 1 == dw);
        asm volatile("s_waitcnt vmcnt(0)" ::: "memory");
        __syncthreads();
        st += 2;
    }

    // epilogue: O^T/l -> LDS transpose.  l = lacc[0] (all regs identical)
    const float inv = 1.0f / lacc[0];
    #pragma unroll
    for (int dt = 0; dt < 4; dt++)
        #pragma unroll
        for (int rr = 0; rr < 4; rr++)
            sm.O[w][c][16 * dt + 4 * g + rr] = ot[dt][rr] * inv;
    // wave-local write->read (per-wave LDS ordering + compiler lgkmcnt)
    const int q = lid >> 2, ch = lid & 3;
    short* dst = y + (base + Qt * 128 + w * 16 + q) * 512 + h * 64 + ch * 16;
    short8v o0, o1;
    #pragma unroll
    for (int j = 0; j < 8; j++) o0[j] = f2bf_h(sm.O[w][q][ch * 16 + j]);
    #pragma unroll
    for (int j = 0; j < 8; j++) o1[j] = f2bf_h(sm.O[w][q][ch * 16 + 8 + j]);
    *(short8v*)dst = o0;
    *(short8v*)(dst + 8) = o1;
}

// ---------------------------------------------------------------------------
// Orchestration
// ---------------------------------------------------------------------------
extern "C" void kernel_launch(void* const* d_in, const int* in_sizes, int n_in,
                              void* d_out, int out_size, void* d_ws, size_t ws_size,
                              hipStream_t stream) {
    const float* x           = (const float*)d_in[0];
    const float* w_qkv       = (const float*)d_in[1];
    const float* b_qkv       = (const float*)d_in[2];
    const float* w_attn_proj = (const float*)d_in[3];
    const float* b_attn_proj = (const float*)d_in[4];
    const float* w_fc        = (const float*)d_in[5];
    const float* b_fc        = (const float*)d_in[6];
    const float* w_mlp_proj  = (const float*)d_in[7];
    const float* b_mlp_proj  = (const float*)d_in[8];
    const float* ln1_g       = (const float*)d_in[9];
    const float* ln1_b       = (const float*)d_in[10];
    const float* ln2_g       = (const float*)d_in[11];
    const float* ln2_b       = (const float*)d_in[12];

    float* out = (float*)d_out;
    short* ws16 = (short*)d_ws;

    // ws layout (bf16 elems), ~65 MB total
    short* wqkvT = ws16;                                   // [1536][512]
    short* waT   = wqkvT + 1536 * 512;                     // [512][512]
    short* wfcT  = waT   + 512 * 512;                      // [2048][512]
    short* wmT   = wfcT  + 2048 * 512;                     // [512][2048]
    short* xn    = wmT   + 512 * 2048;                     // [8192][512]
    short* ybuf  = xn    + (size_t)BT_ * 512;              // [8192][512]
    short* qkvh  = ybuf  + (size_t)BT_ * 512;              // [8192][2048] (q|k|unused, h)
    short* vtb   = qkvh  + (size_t)BT_ * 2048;             // [2][8][64][4096]

    // 0+1) weights -> bf16 transposed AND xn1 = LN(x), one fused launch
    prep_fused<<<3072 + BT_ / 4, 256, 0, stream>>>(
        w_qkv, wqkvT, w_attn_proj, waT, w_fc, wfcT, w_mlp_proj, wmT,
        x, ln1_g, ln1_b, xn);

    // 2) qkv = xn1 @ w_qkv + b_qkv  (bf16 out; V-region fused into Vt)
    gemm_bf16<0, 1, 0, 1><<<12 * 128, 256, 0, stream>>>(
        xn, wqkvT, b_qkv, nullptr, qkvh, BT_, 1536, 512, 12, 16, vtb);

    // 3) y = attention(qkv, Vt)  (bf16 out) — 512 blocks x 8 waves
    attn_mfma<<<512, 512, 0, stream>>>(qkvh, vtb, ybuf);

    // 4) x2 = x + y @ w_attn_proj + b  (f32 out -> d_out)  GX=4 CY=16
    gemm_bf16<0, 0, 1, 0><<<4 * 128, 256, 0, stream>>>(
        ybuf, waT, b_attn_proj, x, out, BT_, 512, 512, 4, 16, nullptr);

    // 5) xn2 = LN(x2)
    ln_bf16<<<BT_ / 4, 256, 0, stream>>>(out, ln2_g, ln2_b, xn);

    // 6) h = gelu(xn2 @ w_fc + b)  (bf16 out)  GX=16 CY=16
    gemm_bf16<1, 1, 0, 0><<<16 * 128, 256, 0, stream>>>(
        xn, wfcT, b_fc, nullptr, qkvh, BT_, 2048, 512, 16, 16, nullptr);

    // 7) out = x2 + h @ w_mlp_proj + b  (f32 out -> d_out)  GX=4 CY=16
    gemm_bf16<0, 0, 1, 0><<<4 * 128, 256, 0, stream>>>(
        qkvh, wmT, b_mlp_proj, out, out, BT_, 512, 2048, 4, 16, nullptr);
}